// Round 8
// baseline (130.242 us; speedup 1.0000x reference)
//
#include <hip/hip_runtime.h>
#include <math.h>

// EPG GRE F0, NP2=64 pulses, V voxels.
// 16 lanes per voxel: lane sub (0..15) holds levels k = 16*j + sub, j<2.
// Packed float2 (re,im) state -> v_pk_fma_f32 complex matvec.
// k-shift = DPP row_ror: ROR1 (P: from lane-1), ROR15 (M: from lane+1).
// ROUND 8: (1) software-pipelined prefetch of next pulse's RF coefficients
// (hide ~120cyc ds_read latency behind the matvec), (2) slot1 fully guarded
// to p in [15,47], (3) launch_bounds(256,8) -> all waves resident.
// Exactness (as R1-R7, passing): levels > p exactly zero on the up-ramp;
// down-ramp junk at level >= 16 after p=47 needs >= 16 down-shifts -> dead.

#define NP2 64
#define ROR1  0x121   // row_ror:1  : dest lane i <- lane (i-1) & 15
#define ROR15 0x12F   // row_ror:15 : dest lane i <- lane (i+1) & 15

typedef float v2f __attribute__((ext_vector_type(2)));

template<int CTRL>
__device__ __forceinline__ float rowrot(float x) {
    return __int_as_float(
        __builtin_amdgcn_mov_dpp(__float_as_int(x), CTRL, 0xF, 0xF, true));
}
template<int CTRL>
__device__ __forceinline__ v2f rowrot2(v2f v) {
    v2f r; r.x = rowrot<CTRL>(v.x); r.y = rowrot<CTRL>(v.y); return r;
}
__device__ __forceinline__ v2f fma2(v2f a, v2f b, v2f c) {
    return __builtin_elementwise_fma(a, b, c);
}
__device__ __forceinline__ v2f spl(float s) { v2f r; r.x = s; r.y = s; return r; }
__device__ __forceinline__ v2f ix(v2f v)   { v2f r; r.x = -v.y; r.y = v.x; return r; }  // i*v

__global__ __launch_bounds__(256, 8) void epg_kernel(
    const float* __restrict__ theta_re,
    const float* __restrict__ theta_im,
    const float* __restrict__ TRp,
    const float* __restrict__ qmaps,
    float* __restrict__ out, int V)
{
    const int t = threadIdx.x;
    const int sub = t & 15;           // lane within voxel group
    const int vloc = t >> 4;          // 0..15 local voxel
    const int v = blockIdx.x * 16 + vloc;

    __shared__ __align__(16) float rf[NP2 + 1][8]; // +1 row: prefetch overrun pad
    __shared__ v2f bufc[16][65];                   // [vloc][pulse] raw F0, +1 pad

    // ---- prologue: lane p computes pulse p's 8 RF coefficients (once) ----
    if (t < NP2) {
        const float tre = theta_re[t], tim = theta_im[t];
        const float a2 = tre * tre + tim * tim;
        const float inva = __frsqrt_rn(a2);        // |theta| >= 0.1
        const float a = a2 * inva;
        const float c = tre * inva, s = tim * inva;
        float sa, ca;
        __sincosf(a, &sa, &ca);
        const float ca2 = 0.5f + 0.5f * ca;        // cos^2(a/2)
        const float sa2 = 0.5f - 0.5f * ca;        // sin^2(a/2)
        const float t1 = (c * c - s * s) * sa2;    // cos(2phi)*sin^2(a/2)
        const float t2 = (2.f * c * s) * sa2;      // sin(2phi)*sin^2(a/2)
        const float t3 = s * sa;
        const float t4 = c * sa;
        rf[t][0] = ca2; rf[t][1] = ca; rf[t][2] = t1; rf[t][3] = t2;
        rf[t][4] = t3;  rf[t][5] = t4; rf[t][6] = 0.5f * t3; rf[t][7] = 0.5f * t4;
    }

    const float T1 = qmaps[V + v];
    const float T2 = qmaps[2 * V + v];
    const float tr = TRp[0];
    const v2f sE1 = spl(__expf(-tr / T1));
    const v2f sE2 = spl(__expf(-tr / T2));
    const float rE1s = (sub == 0) ? (1.0f - sE1.x) : 0.0f;

    // packed state: slot0 = levels sub, slot1 = levels 16+sub
    v2f P0 = spl(0.f), M0 = spl(0.f), Z0 = spl(0.f);
    v2f P1 = spl(0.f), M1 = spl(0.f), Z1 = spl(0.f);
    if (sub == 0) Z0.x = 1.0f;

    __syncthreads();

    const bool s0 = (sub == 0);
    const bool s15 = (sub == 15);

#define MATVEC2(P, M, Z)                                                   \
    {                                                                      \
        const v2f p_ = P, m_ = M, z_ = Z;                                  \
        const v2f ip = ix(p_), im = ix(m_), iz = ix(z_);                   \
        P = fma2(sca2, p_, fma2(st1, m_, fma2(st2, im,                     \
                fma2(st3, z_, st4n * iz))));                               \
        M = fma2(st1, p_, fma2(st2n, ip, fma2(sca2, m_,                    \
                fma2(st3, z_, st4 * iz))));                                \
        Z = fma2(sh3n, p_, fma2(sh4n, ip, fma2(sh3n, m_,                   \
                fma2(sh4, im, sca * z_))));                                \
    }

    // prefetched coefficient registers for the current pulse
    float4 cc0 = *(const float4*)&rf[0][0];
    float4 cc1 = *(const float4*)&rf[0][4];

#pragma unroll 1
    for (int p = 0; p < NP2; ++p) {
        // ---- prefetch pulse p+1 (row 64 is pad; value never used) ----
        const float4 nn0 = *(const float4*)&rf[p + 1][0];
        const float4 nn1 = *(const float4*)&rf[p + 1][4];

        const v2f sca2 = spl(cc0.x), sca = spl(cc0.y);
        const v2f st1 = spl(cc0.z), st2 = spl(cc0.w), st2n = spl(-cc0.w);
        const v2f st3 = spl(cc1.x), st4 = spl(cc1.y), st4n = spl(-cc1.y);
        const v2f sh4 = spl(cc1.w), sh3n = spl(-cc1.z), sh4n = spl(-cc1.w);

        const bool live1 = (p >= 15) && (p <= 47);   // slot1 active (wave-uniform)

        // ---- RF matvec, slot 0 (levels 0..15: always live) ----
        MATVEC2(P0, M0, Z0)
        // ---- slot 1 (levels 16..31: live iff 16 <= min(p,63-p)) ----
        if (p >= 16 && p <= 47) {
            MATVEC2(P1, M1, Z1)
        }
        // raw F0 = P'_0 (sub 0, slot 0); magnitude deferred to epilogue
        if (s0) bufc[vloc][p] = P0;

        if (p < NP2 - 1) {
            // ---- relaxation + shift, slot 0 ----
            P0 *= sE2; M0 *= sE2; Z0 *= sE1;
            const v2f rP0 = rowrot2<ROR1>(P0);
            const v2f rM0 = rowrot2<ROR15>(M0);
            if (live1) {
                // ---- relaxation + shift, slot 1 ----
                P1 *= sE2; M1 *= sE2; Z1 *= sE1;
                const v2f rP1 = rowrot2<ROR1>(P1);
                const v2f rM1 = rowrot2<ROR15>(M1);
                P1.x = s0 ?  rP0.x : rP1.x;     // level16 <- P'_15
                P1.y = s0 ?  rP0.y : rP1.y;
                M1.x = s15 ? 0.f : rM1.x;       // level31 <- M'_32 = 0 exactly
                M1.y = s15 ? 0.f : rM1.y;
                M0.x = s15 ? rM1.x : rM0.x;     // level15 <- M'_16
                M0.y = s15 ? rM1.y : rM0.y;
            } else {
                // phase A: M'_16 == 0 exactly; phase C: level 15 dead -> 0 safe
                M0.x = s15 ? 0.f : rM0.x;
                M0.y = s15 ? 0.f : rM0.y;
            }
            if (!live1) {
                M0.x = s15 ? 0.f : M0.x;        // (kept simple; no-op if taken above)
                M0.y = s15 ? 0.f : M0.y;
            }
            // level0: conj(new M_0) = conj(E2*M'_1); others P_k <- P'_{k-1}
            P0.x = s0 ?  rM0.x : rP0.x;
            P0.y = s0 ? -rM0.y : rP0.y;
            if (!live1) {
                // M path for non-boundary lanes
                M0.x = s15 ? M0.x : rM0.x;
                M0.y = s15 ? M0.y : rM0.y;
            }
            Z0.x += rE1s;
        }

        cc0 = nn0; cc1 = nn1;
    }

    // ---- epilogue: magnitude * PD, coalesced float4 stores ----
    __syncthreads();
    const int r = t >> 4;              // voxel row
    const int c = (t & 15) * 4;        // pulse col
    const float PDr = qmaps[blockIdx.x * 16 + r];
    const v2f a = bufc[r][c], b = bufc[r][c + 1];
    const v2f d = bufc[r][c + 2], e = bufc[r][c + 3];
    float4 val;
    val.x = sqrtf(a.x * a.x + a.y * a.y) * PDr;
    val.y = sqrtf(b.x * b.x + b.y * b.y) * PDr;
    val.z = sqrtf(d.x * d.x + d.y * d.y) * PDr;
    val.w = sqrtf(e.x * e.x + e.y * e.y) * PDr;
    ((float4*)out)[blockIdx.x * 256 + t] = val;
}

extern "C" void kernel_launch(void* const* d_in, const int* in_sizes, int n_in,
                              void* d_out, int out_size, void* d_ws, size_t ws_size,
                              hipStream_t stream) {
    const float* theta_re = (const float*)d_in[0];
    const float* theta_im = (const float*)d_in[1];
    const float* TRp      = (const float*)d_in[2];
    const float* qmaps    = (const float*)d_in[3];
    float* out = (float*)d_out;
    const int V = in_sizes[3] / 3;             // qmaps is [3, V, 1]
    epg_kernel<<<dim3(V / 16), dim3(256), 0, stream>>>(theta_re, theta_im, TRp, qmaps, out, V);
}

// Round 9
// 116.993 us; speedup vs baseline: 1.1132x; 1.1132x over previous
//
#include <hip/hip_runtime.h>
#include <math.h>

// EPG GRE F0, NP2=64 pulses, V voxels.
// 16 lanes per voxel: lane sub (0..15) holds levels k0=sub (slot0), k1=16+sub (slot1).
// ROUND 9: slot-packed r/i-split state: Pr=(P_k0.re,P_k1.re) etc. as float2.
// Complex 3x3 matvec -> 6 real rows x 5 v_pk_fma_f32/v_pk_mul_f32 (inline asm,
// scalar-pair coefficients pre-splatted+pre-negated in LDS; NO half-swaps, NO splats).
// k-shift = DPP row_ror per 32-bit component: ROR1 (P: from lane-1), ROR15 (M: from lane+1).
// Exactness (proof as R1-R8, passing): levels > p are exactly zero on the up-ramp
// (full-width matvec maps 0->0); down-ramp junk at level L needs L down-shifts
// (one per pulse, M path) to reach F0 -> anything at level >= 16 after p=47 is dead;
// the p=63 trailing shift touches only never-read state.

#define NP2 64
#define ROR1  0x121   // row_ror:1  : dest lane i <- lane (i-1) & 15
#define ROR15 0x12F   // row_ror:15 : dest lane i <- lane (i+1) & 15

typedef float v2f __attribute__((ext_vector_type(2)));

template<int CTRL>
__device__ __forceinline__ float rowrot(float x) {
    return __int_as_float(
        __builtin_amdgcn_mov_dpp(__float_as_int(x), CTRL, 0xF, 0xF, true));
}

__device__ __forceinline__ v2f pk_fma(v2f a, v2f b, v2f c) {
    v2f d;
    asm("v_pk_fma_f32 %0, %1, %2, %3" : "=v"(d) : "v"(a), "v"(b), "v"(c));
    return d;
}
__device__ __forceinline__ v2f pk_mul(v2f a, v2f b) {
    v2f d;
    asm("v_pk_mul_f32 %0, %1, %2" : "=v"(d) : "v"(a), "v"(b));
    return d;
}
__device__ __forceinline__ v2f mk2(float a, float b) { v2f r; r.x = a; r.y = b; return r; }

__global__ __launch_bounds__(256, 4) void epg_kernel(
    const float* __restrict__ theta_re,
    const float* __restrict__ theta_im,
    const float* __restrict__ TRp,
    const float* __restrict__ qmaps,
    float* __restrict__ out, int V)
{
    const int t = threadIdx.x;
    const int sub = t & 15;           // lane within voxel group
    const int vloc = t >> 4;          // 0..15 local voxel
    const int v = blockIdx.x * 16 + vloc;

    // coefficient table: 24 floats/pulse = 11 pre-splatted pairs (+pad), 6 x b128
    __shared__ __align__(16) float rf2[NP2][24];
    __shared__ __align__(16) v2f bufc[16][65];   // [vloc][pulse] raw F0 (re,im), +1 pad

    // ---- prologue: lane p computes + splats pulse p's coefficients ----
    if (t < NP2) {
        const float tre = theta_re[t], tim = theta_im[t];
        const float a2 = tre * tre + tim * tim;
        const float inva = __frsqrt_rn(a2);        // |theta| >= 0.1
        const float a = a2 * inva;
        const float c = tre * inva, s = tim * inva;
        float sa, ca;
        __sincosf(a, &sa, &ca);
        const float ca2 = 0.5f + 0.5f * ca;        // cos^2(a/2)
        const float sa2 = 0.5f - 0.5f * ca;        // sin^2(a/2)
        const float t1 = (c * c - s * s) * sa2;    // cos(2phi)*sin^2(a/2)
        const float t2 = (2.f * c * s) * sa2;      // sin(2phi)*sin^2(a/2)
        const float t3 = s * sa;
        const float t4 = c * sa;
        const float h3 = 0.5f * t3, h4 = 0.5f * t4;
        float4 w;
        w = make_float4(ca2, ca2,  t1,  t1); *(float4*)&rf2[t][0]  = w;
        w = make_float4( t2,  t2, -t2, -t2); *(float4*)&rf2[t][4]  = w;
        w = make_float4( t3,  t3,  t4,  t4); *(float4*)&rf2[t][8]  = w;
        w = make_float4(-t4, -t4,  ca,  ca); *(float4*)&rf2[t][12] = w;
        w = make_float4(-h3, -h3,  h4,  h4); *(float4*)&rf2[t][16] = w;
        w = make_float4(-h4, -h4, 0.f, 0.f); *(float4*)&rf2[t][20] = w;
    }

    const float T1 = qmaps[V + v];
    const float T2 = qmaps[2 * V + v];
    const float tr = TRp[0];
    const float E1 = __expf(-tr / T1);
    const float E2 = __expf(-tr / T2);
    const v2f pE1 = mk2(E1, E1);
    const v2f pE2 = mk2(E2, E2);
    const float rE1s = (sub == 0) ? (1.0f - E1) : 0.0f;

    // slot-packed r/i-split state: (level sub, level 16+sub)
    v2f Pr = mk2(0.f, 0.f), Pi = Pr, Mr = Pr, Mi = Pr, Zr = Pr, Zi = Pr;
    if (sub == 0) Zr.x = 1.0f;

    __syncthreads();

    const bool s0 = (sub == 0);
    const bool s15 = (sub == 15);

#pragma unroll 1
    for (int p = 0; p < NP2; ++p) {
        const float4 q0 = *(const float4*)&rf2[p][0];
        const float4 q1 = *(const float4*)&rf2[p][4];
        const float4 q2 = *(const float4*)&rf2[p][8];
        const float4 q3 = *(const float4*)&rf2[p][12];
        const float4 q4 = *(const float4*)&rf2[p][16];
        const float4 q5 = *(const float4*)&rf2[p][20];
        const v2f Cca2 = mk2(q0.x, q0.y), Ct1  = mk2(q0.z, q0.w);
        const v2f Ct2  = mk2(q1.x, q1.y), Cnt2 = mk2(q1.z, q1.w);
        const v2f Ct3  = mk2(q2.x, q2.y), Ct4  = mk2(q2.z, q2.w);
        const v2f Cnt4 = mk2(q3.x, q3.y), Cca  = mk2(q3.z, q3.w);
        const v2f Cnh3 = mk2(q4.x, q4.y), Ch4  = mk2(q4.z, q4.w);
        const v2f Cnh4 = mk2(q5.x, q5.y);

        // ---- RF matvec: 6 real rows, both slots per pk op ----
        const v2f nPr = pk_fma(Cca2, Pr, pk_fma(Ct1,  Mr, pk_fma(Cnt2, Mi, pk_fma(Ct3,  Zr, pk_mul(Ct4,  Zi)))));
        const v2f nPi = pk_fma(Cca2, Pi, pk_fma(Ct2,  Mr, pk_fma(Ct1,  Mi, pk_fma(Cnt4, Zr, pk_mul(Ct3,  Zi)))));
        const v2f nMr = pk_fma(Ct1,  Pr, pk_fma(Ct2,  Pi, pk_fma(Cca2, Mr, pk_fma(Ct3,  Zr, pk_mul(Cnt4, Zi)))));
        const v2f nMi = pk_fma(Cnt2, Pr, pk_fma(Ct1,  Pi, pk_fma(Cca2, Mi, pk_fma(Ct4,  Zr, pk_mul(Ct3,  Zi)))));
        const v2f nZr = pk_fma(Cnh3, Pr, pk_fma(Ch4,  Pi, pk_fma(Cnh3, Mr, pk_fma(Cnh4, Mi, pk_mul(Cca,  Zr)))));
        const v2f nZi = pk_fma(Cnh4, Pr, pk_fma(Cnh3, Pi, pk_fma(Ch4,  Mr, pk_fma(Cnh3, Mi, pk_mul(Cca,  Zi)))));

        // raw F0 = P'_0 (sub0, slot0); magnitude deferred to epilogue
        if (s0) bufc[vloc][p] = mk2(nPr.x, nPi.x);

        // ---- relaxation (packed) ----
        Pr = pk_mul(nPr, pE2); Pi = pk_mul(nPi, pE2);
        Mr = pk_mul(nMr, pE2); Mi = pk_mul(nMi, pE2);
        Zr = pk_mul(nZr, pE1); Zi = pk_mul(nZi, pE1);
        Zr.x += rE1s;

        // ---- shift via DPP row rotate (per 32-bit component) ----
        const float rPrx = rowrot<ROR1>(Pr.x),  rPry = rowrot<ROR1>(Pr.y);
        const float rPix = rowrot<ROR1>(Pi.x),  rPiy = rowrot<ROR1>(Pi.y);
        const float rMrx = rowrot<ROR15>(Mr.x), rMry = rowrot<ROR15>(Mr.y);
        const float rMix = rowrot<ROR15>(Mi.x), rMiy = rowrot<ROR15>(Mi.y);
        // P: level k <- k-1 within slot; sub0 slot1 (lvl16) <- P'_15 (= rP.x at sub0);
        //    sub0 slot0 (lvl0) <- conj(E2*M'_1) (= rM.x at sub0, negated imag)
        Pr.y = s0 ?  rPrx : rPry;
        Pi.y = s0 ?  rPix : rPiy;
        Pr.x = s0 ?  rMrx : rPrx;
        Pi.x = s0 ? -rMix : rPix;
        // M: level k <- k+1 within slot; sub15 slot0 (lvl15) <- M'_16 (= rM.y at sub15);
        //    sub15 slot1 (lvl31) <- M'_32 = 0 exactly
        Mr.x = s15 ? rMry : rMrx;
        Mi.x = s15 ? rMiy : rMix;
        Mr.y = s15 ? 0.f : rMry;
        Mi.y = s15 ? 0.f : rMiy;
    }

    // ---- epilogue: magnitude * PD, coalesced float4 stores ----
    __syncthreads();
    const int r = t >> 4;              // voxel row
    const int c = (t & 15) * 4;        // pulse col
    const float PDr = qmaps[blockIdx.x * 16 + r];
    const v2f a = bufc[r][c],     b = bufc[r][c + 1];
    const v2f d = bufc[r][c + 2], e = bufc[r][c + 3];
    float4 val;
    val.x = sqrtf(a.x * a.x + a.y * a.y) * PDr;
    val.y = sqrtf(b.x * b.x + b.y * b.y) * PDr;
    val.z = sqrtf(d.x * d.x + d.y * d.y) * PDr;
    val.w = sqrtf(e.x * e.x + e.y * e.y) * PDr;
    ((float4*)out)[blockIdx.x * 256 + t] = val;
}

extern "C" void kernel_launch(void* const* d_in, const int* in_sizes, int n_in,
                              void* d_out, int out_size, void* d_ws, size_t ws_size,
                              hipStream_t stream) {
    const float* theta_re = (const float*)d_in[0];
    const float* theta_im = (const float*)d_in[1];
    const float* TRp      = (const float*)d_in[2];
    const float* qmaps    = (const float*)d_in[3];
    float* out = (float*)d_out;
    const int V = in_sizes[3] / 3;             // qmaps is [3, V, 1]
    epg_kernel<<<dim3(V / 16), dim3(256), 0, stream>>>(theta_re, theta_im, TRp, qmaps, out, V);
}

// Round 10
// 115.317 us; speedup vs baseline: 1.1294x; 1.0145x over previous
//
#include <hip/hip_runtime.h>
#include <math.h>

// EPG GRE F0, NP2=64 pulses, V voxels.
// 16 lanes per voxel: lane sub (0..15) holds levels k0=sub (slot0), k1=16+sub (slot1).
// Slot-packed r/i-split state (Pr=(P_k0.re,P_k1.re) etc.) -> v_pk_fma_f32 rows.
// ROUND 10: coefficient stream moved OFF the vector pipe: a pre-kernel writes the
// pre-splatted pair table [65][24] to d_ws; the main loop streams it with
// s_load_dwordx8 (SGPRs, scalar pipe), double-buffered with a tied-operand
// s_waitcnt so ordering is enforced by data deps. pk-FMAs take the coefficient
// SGPR pairs directly (VOP3P scalar operand) -> no splats, no hot-loop ds_reads.
// k-shift = DPP row_ror per component: ROR1 (P: from lane-1), ROR15 (M: from lane+1).
// Exactness (proof as R1-R9, passing): up-ramp levels > p are exactly zero;
// down-ramp junk at level L needs L down-shifts (one per pulse, M path) to reach
// F0 -> anything at level >= 16 after p=47 is dead; trailing p=63 shift touches
// only never-read state.

#define NP2 64
#define ROR1  0x121   // row_ror:1  : dest lane i <- lane (i-1) & 15
#define ROR15 0x12F   // row_ror:15 : dest lane i <- lane (i+1) & 15

typedef float v2f __attribute__((ext_vector_type(2)));
typedef float v8f __attribute__((ext_vector_type(8)));

template<int CTRL>
__device__ __forceinline__ float rowrot(float x) {
    return __int_as_float(
        __builtin_amdgcn_mov_dpp(__float_as_int(x), CTRL, 0xF, 0xF, true));
}
__device__ __forceinline__ v2f mk2(float a, float b) { v2f r; r.x = a; r.y = b; return r; }

#define PAIR(V, i)  __builtin_shufflevector((V), (V), (i), (i) + 1)
#define FMA2(a, b, c) __builtin_elementwise_fma((a), (b), (c))

// ---- pre-kernel: build the pre-splatted coefficient pair table in d_ws ----
// row p (24 floats): [ca2,ca2, t1,t1, t2,t2, -t2,-t2][t3,t3, t4,t4, -t4,-t4, ca,ca]
//                    [-h3,-h3, h4,h4, -h4,-h4, 0,0]; row 64 = zero pad (prefetch target)
__global__ void coef_kernel(const float* __restrict__ theta_re,
                            const float* __restrict__ theta_im,
                            float* __restrict__ cw)
{
    const int t = threadIdx.x;
    if (t < NP2) {
        const float tre = theta_re[t], tim = theta_im[t];
        const float a2 = tre * tre + tim * tim;
        const float inva = __frsqrt_rn(a2);        // |theta| >= 0.1
        const float a = a2 * inva;
        const float c = tre * inva, s = tim * inva;
        float sa, ca;
        __sincosf(a, &sa, &ca);
        const float ca2 = 0.5f + 0.5f * ca;        // cos^2(a/2)
        const float sa2 = 0.5f - 0.5f * ca;        // sin^2(a/2)
        const float t1 = (c * c - s * s) * sa2;    // cos(2phi)*sin^2(a/2)
        const float t2 = (2.f * c * s) * sa2;      // sin(2phi)*sin^2(a/2)
        const float t3 = s * sa, t4 = c * sa;
        const float h3 = 0.5f * t3, h4 = 0.5f * t4;
        float4* row = (float4*)(cw + t * 24);
        row[0] = make_float4(ca2, ca2,  t1,  t1);
        row[1] = make_float4( t2,  t2, -t2, -t2);
        row[2] = make_float4( t3,  t3,  t4,  t4);
        row[3] = make_float4(-t4, -t4,  ca,  ca);
        row[4] = make_float4(-h3, -h3,  h4,  h4);
        row[5] = make_float4(-h4, -h4, 0.f, 0.f);
    } else if (t < NP2 + 6) {
        ((float4*)(cw + NP2 * 24))[t - NP2] = make_float4(0.f, 0.f, 0.f, 0.f);
    }
}

__global__ __launch_bounds__(256, 8) void epg_kernel(
    const float* __restrict__ TRp,
    const float* __restrict__ qmaps,
    const float* __restrict__ cw,
    float* __restrict__ out, int V)
{
    const int t = threadIdx.x;
    const int sub = t & 15;           // lane within voxel group
    const int vloc = t >> 4;          // 0..15 local voxel
    const int v = blockIdx.x * 16 + vloc;

    __shared__ __align__(16) v2f bufc[16][65];   // [vloc][pulse] raw F0 (re,im), +1 pad

    const float T1 = qmaps[V + v];
    const float T2 = qmaps[2 * V + v];
    const float tr = TRp[0];
    const float E1 = __expf(-tr / T1);
    const float E2 = __expf(-tr / T2);
    const v2f pE1 = mk2(E1, E1);
    const v2f pE2 = mk2(E2, E2);
    const float rE1s = (sub == 0) ? (1.0f - E1) : 0.0f;

    // slot-packed r/i-split state: (level sub, level 16+sub)
    v2f Pr = mk2(0.f, 0.f), Pi = Pr, Mr = Pr, Mi = Pr, Zr = Pr, Zi = Pr;
    if (sub == 0) Zr.x = 1.0f;

    const bool s0 = (sub == 0);
    const bool s15 = (sub == 15);

    // ---- SMEM double-buffered coefficient stream (SGPRs, scalar pipe) ----
    v8f A0, A1, A2, B0, B1, B2;
    asm volatile("s_load_dwordx8 %0, %1, 0x0"  : "=s"(B0) : "s"(cw));
    asm volatile("s_load_dwordx8 %0, %1, 0x20" : "=s"(B1) : "s"(cw));
    asm volatile("s_load_dwordx8 %0, %1, 0x40" : "=s"(B2) : "s"(cw));
    asm volatile("s_waitcnt lgkmcnt(0)"
                 : "=s"(A0), "=s"(A1), "=s"(A2) : "0"(B0), "1"(B1), "2"(B2));

#pragma unroll 1
    for (int p = 0; p < NP2; ++p) {
        // issue next pulse's scalar loads (row 64 = zero pad, never consumed)
        const float* nx = cw + (p + 1) * 24;
        asm volatile("s_load_dwordx8 %0, %1, 0x0"  : "=s"(B0) : "s"(nx));
        asm volatile("s_load_dwordx8 %0, %1, 0x20" : "=s"(B1) : "s"(nx));
        asm volatile("s_load_dwordx8 %0, %1, 0x40" : "=s"(B2) : "s"(nx));

        const v2f Cca2 = PAIR(A0, 0), Ct1  = PAIR(A0, 2);
        const v2f Ct2  = PAIR(A0, 4), Cnt2 = PAIR(A0, 6);
        const v2f Ct3  = PAIR(A1, 0), Ct4  = PAIR(A1, 2);
        const v2f Cnt4 = PAIR(A1, 4), Cca  = PAIR(A1, 6);
        const v2f Cnh3 = PAIR(A2, 0), Ch4  = PAIR(A2, 2), Cnh4 = PAIR(A2, 4);

        // ---- RF matvec: 6 real rows, both slots per packed op ----
        const v2f nPr = FMA2(Cca2, Pr, FMA2(Ct1,  Mr, FMA2(Cnt2, Mi, FMA2(Ct3,  Zr, Ct4  * Zi))));
        const v2f nPi = FMA2(Cca2, Pi, FMA2(Ct2,  Mr, FMA2(Ct1,  Mi, FMA2(Cnt4, Zr, Ct3  * Zi))));
        const v2f nMr = FMA2(Ct1,  Pr, FMA2(Ct2,  Pi, FMA2(Cca2, Mr, FMA2(Ct3,  Zr, Cnt4 * Zi))));
        const v2f nMi = FMA2(Cnt2, Pr, FMA2(Ct1,  Pi, FMA2(Cca2, Mi, FMA2(Ct4,  Zr, Ct3  * Zi))));
        const v2f nZr = FMA2(Cnh3, Pr, FMA2(Ch4,  Pi, FMA2(Cnh3, Mr, FMA2(Cnh4, Mi, Cca  * Zr))));
        const v2f nZi = FMA2(Cnh4, Pr, FMA2(Cnh3, Pi, FMA2(Ch4,  Mr, FMA2(Cnh3, Mi, Cca  * Zi))));

        // raw F0 = P'_0 (sub0, slot0); magnitude deferred to epilogue
        if (s0) bufc[vloc][p] = mk2(nPr.x, nPi.x);

        // ---- relaxation (packed) ----
        Pr = nPr * pE2; Pi = nPi * pE2;
        Mr = nMr * pE2; Mi = nMi * pE2;
        Zr = nZr * pE1; Zi = nZi * pE1;
        Zr.x += rE1s;

        // ---- shift via DPP row rotate (per 32-bit component) ----
        const float rPrx = rowrot<ROR1>(Pr.x),  rPry = rowrot<ROR1>(Pr.y);
        const float rPix = rowrot<ROR1>(Pi.x),  rPiy = rowrot<ROR1>(Pi.y);
        const float rMrx = rowrot<ROR15>(Mr.x), rMry = rowrot<ROR15>(Mr.y);
        const float rMix = rowrot<ROR15>(Mi.x), rMiy = rowrot<ROR15>(Mi.y);
        // P: level k <- k-1 within slot; sub0 slot1 (lvl16) <- P'_15;
        //    sub0 slot0 (lvl0) <- conj(E2*M'_1)
        Pr.y = s0 ?  rPrx : rPry;
        Pi.y = s0 ?  rPix : rPiy;
        Pr.x = s0 ?  rMrx : rPrx;
        Pi.x = s0 ? -rMix : rPix;
        // M: level k <- k+1 within slot; sub15 slot0 (lvl15) <- M'_16;
        //    sub15 slot1 (lvl31) <- M'_32 = 0 exactly
        Mr.x = s15 ? rMry : rMrx;
        Mi.x = s15 ? rMiy : rMix;
        Mr.y = s15 ? 0.f : rMry;
        Mi.y = s15 ? 0.f : rMiy;

        // consume the prefetched buffers only after they have landed:
        // tied-operand waitcnt makes the dependency explicit (and is the only
        // instruction emitted -- regalloc coalesces A=B).
        asm volatile("s_waitcnt lgkmcnt(0)"
                     : "=s"(A0), "=s"(A1), "=s"(A2) : "0"(B0), "1"(B1), "2"(B2));
    }

    // ---- epilogue: magnitude * PD, coalesced float4 stores ----
    __syncthreads();
    const int r = t >> 4;              // voxel row
    const int c = (t & 15) * 4;        // pulse col
    const float PDr = qmaps[blockIdx.x * 16 + r];
    const v2f a = bufc[r][c],     b = bufc[r][c + 1];
    const v2f d = bufc[r][c + 2], e = bufc[r][c + 3];
    float4 val;
    val.x = sqrtf(a.x * a.x + a.y * a.y) * PDr;
    val.y = sqrtf(b.x * b.x + b.y * b.y) * PDr;
    val.z = sqrtf(d.x * d.x + d.y * d.y) * PDr;
    val.w = sqrtf(e.x * e.x + e.y * e.y) * PDr;
    ((float4*)out)[blockIdx.x * 256 + t] = val;
}

extern "C" void kernel_launch(void* const* d_in, const int* in_sizes, int n_in,
                              void* d_out, int out_size, void* d_ws, size_t ws_size,
                              hipStream_t stream) {
    const float* theta_re = (const float*)d_in[0];
    const float* theta_im = (const float*)d_in[1];
    const float* TRp      = (const float*)d_in[2];
    const float* qmaps    = (const float*)d_in[3];
    float* out = (float*)d_out;
    float* cw  = (float*)d_ws;                 // [65][24] floats = 6240 B
    const int V = in_sizes[3] / 3;             // qmaps is [3, V, 1]
    coef_kernel<<<dim3(1), dim3(128), 0, stream>>>(theta_re, theta_im, cw);
    epg_kernel<<<dim3(V / 16), dim3(256), 0, stream>>>(TRp, qmaps, cw, out, V);
}

// Round 11
// 109.020 us; speedup vs baseline: 1.1947x; 1.0578x over previous
//
#include <hip/hip_runtime.h>
#include <math.h>

// EPG GRE F0, NP2=64 pulses, V voxels.
// 16 lanes per voxel: lane sub (0..15) holds levels k0=sub (slot0), k1=16+sub (slot1).
// Slot-packed r/i-split state (Pr=(P_k0.re,P_k1.re) etc.), v_pk_fma_f32 rows,
// SMEM-streamed coefficients (scalar pipe, double-buffered).
// ROUND 11: Rz-factorization T(a,phi) = P(phi) T0(a) P(-phi), state kept in the
// accumulated-phase frame (P(phi) commutes with shift/relax/recovery AND the conj
// boundary: conj maps the F- frame phase to the F+ frame phase). Per pulse only one
// residual rotation by delta_p = phi_{p-1}-phi_p remains, fused with the DEFERRED
// relaxation of the previous pulse (E2 into the delta products, E1+recovery into Z;
// Z=1 init is self-consistent: E1*1+(1-E1)=1). |F~0| = |F0| so magnitude output
// is frame-invariant. 36 pk -> 28 pk per pulse (FP32 pipe = 4 cyc per pk op).
// Exactness (proof as R1-R10, passing): up-ramp levels > p are exactly zero;
// down-ramp junk at level L needs L down-shifts to reach F0 -> levels >= 16 after
// p=47 are dead; trailing p=63 shift touches only never-read state.

#define NP2 64
#define ROR1  0x121   // row_ror:1  : dest lane i <- lane (i-1) & 15
#define ROR15 0x12F   // row_ror:15 : dest lane i <- lane (i+1) & 15

typedef float v2f __attribute__((ext_vector_type(2)));
typedef float v8f __attribute__((ext_vector_type(8)));

template<int CTRL>
__device__ __forceinline__ float rowrot(float x) {
    return __int_as_float(
        __builtin_amdgcn_mov_dpp(__float_as_int(x), CTRL, 0xF, 0xF, true));
}
__device__ __forceinline__ v2f mk2(float a, float b) { v2f r; r.x = a; r.y = b; return r; }

#define PAIR(V, i)  __builtin_shufflevector((V), (V), (i), (i) + 1)
#define FMA2(a, b, c) __builtin_elementwise_fma((a), (b), (c))

// ---- pre-kernel: coefficient pair table [65][16] in d_ws ----
// row p: [cd,cd, sd,sd, ca2,ca2, sa2,sa2][sa,sa, ca,ca, h,h, 0,0]
// cd+i*sd = e^{i(phi_{p-1}-phi_p)} built from unit vectors (no atan2); phi_{-1}=0.
__global__ void coef_kernel(const float* __restrict__ theta_re,
                            const float* __restrict__ theta_im,
                            float* __restrict__ cw)
{
    const int t = threadIdx.x;
    if (t < NP2) {
        const float tre = theta_re[t], tim = theta_im[t];
        const float a2 = tre * tre + tim * tim;
        const float inva = __frsqrt_rn(a2);        // |theta| >= 0.1
        const float a = a2 * inva;
        const float c = tre * inva, s = tim * inva;   // cos/sin(phi_p)
        float cp = 1.f, sp = 0.f;                     // cos/sin(phi_{p-1})
        if (t > 0) {
            const float ure = theta_re[t - 1], uim = theta_im[t - 1];
            const float ia = __frsqrt_rn(ure * ure + uim * uim);
            cp = ure * ia; sp = uim * ia;
        }
        const float cd = cp * c + sp * s;          // cos(phi_{p-1}-phi_p)
        const float sd = sp * c - cp * s;          // sin(phi_{p-1}-phi_p)
        float sa, ca;
        __sincosf(a, &sa, &ca);
        const float ca2 = 0.5f + 0.5f * ca;        // cos^2(a/2)
        const float sa2 = 0.5f - 0.5f * ca;        // sin^2(a/2)
        const float h = 0.5f * sa;
        float4* row = (float4*)(cw + t * 16);
        row[0] = make_float4(cd, cd, sd, sd);
        row[1] = make_float4(ca2, ca2, sa2, sa2);
        row[2] = make_float4(sa, sa, ca, ca);
        row[3] = make_float4(h, h, 0.f, 0.f);
    } else if (t < NP2 + 4) {
        ((float4*)(cw + NP2 * 16))[t - NP2] = make_float4(0.f, 0.f, 0.f, 0.f);
    }
}

__global__ __launch_bounds__(256, 8) void epg_kernel(
    const float* __restrict__ TRp,
    const float* __restrict__ qmaps,
    const float* __restrict__ cw,
    float* __restrict__ out, int V)
{
    const int t = threadIdx.x;
    const int sub = t & 15;           // lane within voxel group
    const int vloc = t >> 4;          // 0..15 local voxel
    const int v = blockIdx.x * 16 + vloc;

    __shared__ __align__(16) v2f bufc[16][65];   // [vloc][pulse] raw F~0 (re,im), +1 pad

    const float T1 = qmaps[V + v];
    const float T2 = qmaps[2 * V + v];
    const float tr = TRp[0];
    const float E1 = __expf(-tr / T1);
    const float E2 = __expf(-tr / T2);
    const v2f pE1 = mk2(E1, E1);
    const v2f pE2 = mk2(E2, E2);
    const float rE1s = (sub == 0) ? (1.0f - E1) : 0.0f;

    // slot-packed r/i-split state in the accumulated-phase frame, UNRELAXED
    // (relax of pulse p-1 is applied in pulse p's input stage).
    v2f Pr = mk2(0.f, 0.f), Pi = Pr, Mr = Pr, Mi = Pr, Zr = Pr, Zi = Pr;
    if (sub == 0) Zr.x = 1.0f;   // E1*1 + (1-E1) = 1 at p=0: exact

    const bool s0 = (sub == 0);
    const bool s15 = (sub == 15);

    // ---- SMEM double-buffered coefficient stream (scalar pipe) ----
    v8f A0, A1, B0, B1;
    asm volatile("s_load_dwordx8 %0, %1, 0x0"  : "=s"(B0) : "s"(cw));
    asm volatile("s_load_dwordx8 %0, %1, 0x20" : "=s"(B1) : "s"(cw));
    asm volatile("s_waitcnt lgkmcnt(0)"
                 : "=s"(A0), "=s"(A1) : "0"(B0), "1"(B1));

#pragma unroll 1
    for (int p = 0; p < NP2; ++p) {
        // issue next pulse's scalar loads (row 64 = zero pad, never consumed)
        const float* nx = cw + (p + 1) * 16;
        asm volatile("s_load_dwordx8 %0, %1, 0x0"  : "=s"(B0) : "s"(nx));
        asm volatile("s_load_dwordx8 %0, %1, 0x20" : "=s"(B1) : "s"(nx));

        const v2f Ccd  = PAIR(A0, 0), Csd  = PAIR(A0, 2);
        const v2f Cca2 = PAIR(A0, 4), Csa2 = PAIR(A0, 6);
        const v2f Csa  = PAIR(A1, 0), Cca  = PAIR(A1, 2), Ch = PAIR(A1, 4);

        // ---- input stage: deferred relax (E2, E1+recovery) fused with the
        //      inter-pulse frame rotation by delta_p (F+ gets e^{+id}, F- e^{-id}) ----
        const v2f ec = pE2 * Ccd, es = pE2 * Csd;
        const v2f hPr = FMA2(ec, Pr, -(es * Pi));
        const v2f hPi = FMA2(ec, Pi,  (es * Pr));
        const v2f hMr = FMA2(ec, Mr,  (es * Mi));
        const v2f hMi = FMA2(ec, Mi, -(es * Mr));
        v2f ezr = pE1 * Zr;
        const v2f ezi = pE1 * Zi;
        ezr.x += rE1s;

        // ---- T0(a): real/pure-imaginary structured mix ----
        const v2f szr = Csa * ezr, szi = Csa * ezi;
        const v2f nPr = FMA2(Cca2, hPr, FMA2(Csa2, hMr,  szi));
        const v2f nPi = FMA2(Cca2, hPi, FMA2(Csa2, hMi, -szr));
        const v2f nMr = FMA2(Csa2, hPr, FMA2(Cca2, hMr, -szi));
        const v2f nMi = FMA2(Csa2, hPi, FMA2(Cca2, hMi,  szr));
        const v2f d1 = hPi - hMi, d2 = hMr - hPr;
        const v2f nZr = FMA2(Ch, d1, Cca * ezr);
        const v2f nZi = FMA2(Ch, d2, Cca * ezi);

        // raw F~0 = P'_0 (sub0, slot0); |F~0| = |F0| (frame-invariant)
        if (s0) bufc[vloc][p] = mk2(nPr.x, nPi.x);

        Zr = nZr; Zi = nZi;   // Z does not shift; relax deferred

        // ---- shift via DPP row rotate (on UNRELAXED matvec outputs) ----
        const float rPrx = rowrot<ROR1>(nPr.x),  rPry = rowrot<ROR1>(nPr.y);
        const float rPix = rowrot<ROR1>(nPi.x),  rPiy = rowrot<ROR1>(nPi.y);
        const float rMrx = rowrot<ROR15>(nMr.x), rMry = rowrot<ROR15>(nMr.y);
        const float rMix = rowrot<ROR15>(nMi.x), rMiy = rowrot<ROR15>(nMi.y);
        // P: level k <- k-1 within slot; sub0 slot1 (lvl16) <- P'_15;
        //    sub0 slot0 (lvl0) <- conj(M'_1)   (E2 applied next pulse; E2 real)
        Pr.y = s0 ?  rPrx : rPry;
        Pi.y = s0 ?  rPix : rPiy;
        Pr.x = s0 ?  rMrx : rPrx;
        Pi.x = s0 ? -rMix : rPix;
        // M: level k <- k+1 within slot; sub15 slot0 (lvl15) <- M'_16;
        //    sub15 slot1 (lvl31) <- M'_32 = 0 exactly
        Mr.x = s15 ? rMry : rMrx;
        Mi.x = s15 ? rMiy : rMix;
        Mr.y = s15 ? 0.f : rMry;
        Mi.y = s15 ? 0.f : rMiy;

        // consume prefetched coefficient buffers only after they land
        asm volatile("s_waitcnt lgkmcnt(0)"
                     : "=s"(A0), "=s"(A1) : "0"(B0), "1"(B1));
    }

    // ---- epilogue: magnitude * PD, coalesced float4 stores ----
    __syncthreads();
    const int r = t >> 4;              // voxel row
    const int c = (t & 15) * 4;        // pulse col
    const float PDr = qmaps[blockIdx.x * 16 + r];
    const v2f a = bufc[r][c],     b = bufc[r][c + 1];
    const v2f d = bufc[r][c + 2], e = bufc[r][c + 3];
    float4 val;
    val.x = sqrtf(a.x * a.x + a.y * a.y) * PDr;
    val.y = sqrtf(b.x * b.x + b.y * b.y) * PDr;
    val.z = sqrtf(d.x * d.x + d.y * d.y) * PDr;
    val.w = sqrtf(e.x * e.x + e.y * e.y) * PDr;
    ((float4*)out)[blockIdx.x * 256 + t] = val;
}

extern "C" void kernel_launch(void* const* d_in, const int* in_sizes, int n_in,
                              void* d_out, int out_size, void* d_ws, size_t ws_size,
                              hipStream_t stream) {
    const float* theta_re = (const float*)d_in[0];
    const float* theta_im = (const float*)d_in[1];
    const float* TRp      = (const float*)d_in[2];
    const float* qmaps    = (const float*)d_in[3];
    float* out = (float*)d_out;
    float* cw  = (float*)d_ws;                 // [65][16] floats = 4160 B
    const int V = in_sizes[3] / 3;             // qmaps is [3, V, 1]
    coef_kernel<<<dim3(1), dim3(128), 0, stream>>>(theta_re, theta_im, cw);
    epg_kernel<<<dim3(V / 16), dim3(256), 0, stream>>>(TRp, qmaps, cw, out, V);
}

// Round 12
// 108.615 us; speedup vs baseline: 1.1991x; 1.0037x over previous
//
#include <hip/hip_runtime.h>
#include <math.h>

// EPG GRE F0, NP2=64 pulses, V voxels.
// 16 lanes per voxel: lane sub (0..15) holds levels k0=sub (slot0), k1=16+sub (slot1).
// Slot-packed r/i-split state, v_pk_fma_f32 rows, SMEM-streamed coefficients.
// Rz-factorized RF (R11): one residual delta_p rotation fused with deferred relax.
// ROUND 12: TWO VOXELS PER LANE (A: vloc, B: vloc+16). HW sustains only ~16
// waves/CU regardless of launch_bounds (R4-R11 occupancy ~50%), so the ~45%
// issue stall (VALUBusy 72%) is chain-latency -> give each wave two independent
// dependency chains (ILP) instead of more waves (TLP). Grid halves to V/32.
// Exactness (proof as R1-R11, passing): up-ramp levels > p exactly zero;
// down-ramp junk at level L needs L down-shifts to reach F0 -> levels >= 16
// after p=47 dead; trailing p=63 shift touches only never-read state.

#define NP2 64
#define ROR1  0x121   // row_ror:1  : dest lane i <- lane (i-1) & 15
#define ROR15 0x12F   // row_ror:15 : dest lane i <- lane (i+1) & 15

typedef float v2f __attribute__((ext_vector_type(2)));
typedef float v8f __attribute__((ext_vector_type(8)));

template<int CTRL>
__device__ __forceinline__ float rowrot(float x) {
    return __int_as_float(
        __builtin_amdgcn_mov_dpp(__float_as_int(x), CTRL, 0xF, 0xF, true));
}
__device__ __forceinline__ v2f mk2(float a, float b) { v2f r; r.x = a; r.y = b; return r; }

#define PAIR(V, i)  __builtin_shufflevector((V), (V), (i), (i) + 1)
#define FMA2(a, b, c) __builtin_elementwise_fma((a), (b), (c))

// ---- pre-kernel: coefficient pair table [65][16] in d_ws ----
// row p: [cd,cd, sd,sd, ca2,ca2, sa2,sa2][sa,sa, ca,ca, h,h, 0,0]
// cd+i*sd = e^{i(phi_{p-1}-phi_p)} from unit vectors (no atan2); phi_{-1}=0.
__global__ void coef_kernel(const float* __restrict__ theta_re,
                            const float* __restrict__ theta_im,
                            float* __restrict__ cw)
{
    const int t = threadIdx.x;
    if (t < NP2) {
        const float tre = theta_re[t], tim = theta_im[t];
        const float a2 = tre * tre + tim * tim;
        const float inva = __frsqrt_rn(a2);        // |theta| >= 0.1
        const float a = a2 * inva;
        const float c = tre * inva, s = tim * inva;   // cos/sin(phi_p)
        float cp = 1.f, sp = 0.f;                     // cos/sin(phi_{p-1})
        if (t > 0) {
            const float ure = theta_re[t - 1], uim = theta_im[t - 1];
            const float ia = __frsqrt_rn(ure * ure + uim * uim);
            cp = ure * ia; sp = uim * ia;
        }
        const float cd = cp * c + sp * s;          // cos(phi_{p-1}-phi_p)
        const float sd = sp * c - cp * s;          // sin(phi_{p-1}-phi_p)
        float sa, ca;
        __sincosf(a, &sa, &ca);
        const float ca2 = 0.5f + 0.5f * ca;        // cos^2(a/2)
        const float sa2 = 0.5f - 0.5f * ca;        // sin^2(a/2)
        const float h = 0.5f * sa;
        float4* row = (float4*)(cw + t * 16);
        row[0] = make_float4(cd, cd, sd, sd);
        row[1] = make_float4(ca2, ca2, sa2, sa2);
        row[2] = make_float4(sa, sa, ca, ca);
        row[3] = make_float4(h, h, 0.f, 0.f);
    } else if (t < NP2 + 4) {
        ((float4*)(cw + NP2 * 16))[t - NP2] = make_float4(0.f, 0.f, 0.f, 0.f);
    }
}

struct St { v2f Pr, Pi, Mr, Mi, Zr, Zi; };

// one pulse for one voxel's state; returns raw F~0 pair (valid on sub0 lanes)
__device__ __forceinline__ v2f step(St& S,
    v2f Ccd, v2f Csd, v2f Cca2, v2f Csa2, v2f Csa, v2f Cca, v2f Ch,
    v2f pE1, v2f pE2, v2f rec, bool s0, bool s15)
{
    // deferred relax (E2,E1+recovery) fused with the delta_p frame rotation
    const v2f ec = pE2 * Ccd, es = pE2 * Csd;
    const v2f hPr = FMA2(ec, S.Pr, -(es * S.Pi));
    const v2f hPi = FMA2(ec, S.Pi,  (es * S.Pr));
    const v2f hMr = FMA2(ec, S.Mr,  (es * S.Mi));
    const v2f hMi = FMA2(ec, S.Mi, -(es * S.Mr));
    const v2f ezr = FMA2(pE1, S.Zr, rec);
    const v2f ezi = pE1 * S.Zi;
    // T0(a): real / pure-imaginary structured mix
    const v2f szr = Csa * ezr, szi = Csa * ezi;
    const v2f nPr = FMA2(Cca2, hPr, FMA2(Csa2, hMr,  szi));
    const v2f nPi = FMA2(Cca2, hPi, FMA2(Csa2, hMi, -szr));
    const v2f nMr = FMA2(Csa2, hPr, FMA2(Cca2, hMr, -szi));
    const v2f nMi = FMA2(Csa2, hPi, FMA2(Cca2, hMi,  szr));
    const v2f d1 = hPi - hMi, d2 = hMr - hPr;
    S.Zr = FMA2(Ch, d1, Cca * ezr);
    S.Zi = FMA2(Ch, d2, Cca * ezi);
    // shift via DPP row rotate (on UNRELAXED outputs; relax applied next pulse)
    const float rPrx = rowrot<ROR1>(nPr.x),  rPry = rowrot<ROR1>(nPr.y);
    const float rPix = rowrot<ROR1>(nPi.x),  rPiy = rowrot<ROR1>(nPi.y);
    const float rMrx = rowrot<ROR15>(nMr.x), rMry = rowrot<ROR15>(nMr.y);
    const float rMix = rowrot<ROR15>(nMi.x), rMiy = rowrot<ROR15>(nMi.y);
    // P: level k <- k-1 within slot; sub0 slot1 (lvl16) <- P'_15;
    //    sub0 slot0 (lvl0) <- conj(M'_1)  (E2 next pulse; E2 real)
    S.Pr.y = s0 ?  rPrx : rPry;
    S.Pi.y = s0 ?  rPix : rPiy;
    S.Pr.x = s0 ?  rMrx : rPrx;
    S.Pi.x = s0 ? -rMix : rPix;
    // M: level k <- k+1 within slot; sub15 slot0 (lvl15) <- M'_16;
    //    sub15 slot1 (lvl31) <- M'_32 = 0 exactly
    S.Mr.x = s15 ? rMry : rMrx;
    S.Mi.x = s15 ? rMiy : rMix;
    S.Mr.y = s15 ? 0.f : rMry;
    S.Mi.y = s15 ? 0.f : rMiy;
    return mk2(nPr.x, nPi.x);
}

__global__ __launch_bounds__(256, 8) void epg_kernel(
    const float* __restrict__ TRp,
    const float* __restrict__ qmaps,
    const float* __restrict__ cw,
    float* __restrict__ out, int V)
{
    const int t = threadIdx.x;
    const int sub = t & 15;           // lane within voxel group
    const int vloc = t >> 4;          // 0..15
    const int vA = blockIdx.x * 32 + vloc;
    const int vB = vA + 16;

    __shared__ __align__(16) v2f bufc[32][65];   // [vloc][pulse] raw F~0, +1 pad

    const float tr = TRp[0];
    const float E1A = __expf(-tr / qmaps[V + vA]);
    const float E2A = __expf(-tr / qmaps[2 * V + vA]);
    const float E1B = __expf(-tr / qmaps[V + vB]);
    const float E2B = __expf(-tr / qmaps[2 * V + vB]);
    const bool s0 = (sub == 0);
    const bool s15 = (sub == 15);
    const v2f pE1A = mk2(E1A, E1A), pE2A = mk2(E2A, E2A);
    const v2f pE1B = mk2(E1B, E1B), pE2B = mk2(E2B, E2B);
    const v2f recA = mk2(s0 ? (1.f - E1A) : 0.f, 0.f);
    const v2f recB = mk2(s0 ? (1.f - E1B) : 0.f, 0.f);

    St A, B;
    A.Pr = mk2(0.f, 0.f); A.Pi = A.Pr; A.Mr = A.Pr; A.Mi = A.Pr; A.Zr = A.Pr; A.Zi = A.Pr;
    B = A;
    if (s0) { A.Zr.x = 1.0f; B.Zr.x = 1.0f; }   // E1*1 + (1-E1) = 1: exact at p=0

    // ---- SMEM double-buffered coefficient stream (scalar pipe) ----
    v8f A0, A1, B0, B1;
    asm volatile("s_load_dwordx8 %0, %1, 0x0"  : "=s"(B0) : "s"(cw));
    asm volatile("s_load_dwordx8 %0, %1, 0x20" : "=s"(B1) : "s"(cw));
    asm volatile("s_waitcnt lgkmcnt(0)"
                 : "=s"(A0), "=s"(A1) : "0"(B0), "1"(B1));

#pragma unroll 1
    for (int p = 0; p < NP2; ++p) {
        // issue next pulse's scalar loads (row 64 = zero pad, never consumed)
        const float* nx = cw + (p + 1) * 16;
        asm volatile("s_load_dwordx8 %0, %1, 0x0"  : "=s"(B0) : "s"(nx));
        asm volatile("s_load_dwordx8 %0, %1, 0x20" : "=s"(B1) : "s"(nx));

        const v2f Ccd  = PAIR(A0, 0), Csd  = PAIR(A0, 2);
        const v2f Cca2 = PAIR(A0, 4), Csa2 = PAIR(A0, 6);
        const v2f Csa  = PAIR(A1, 0), Cca  = PAIR(A1, 2), Ch = PAIR(A1, 4);

        // two independent voxels per lane: two dependency chains to interleave
        const v2f f0a = step(A, Ccd, Csd, Cca2, Csa2, Csa, Cca, Ch,
                             pE1A, pE2A, recA, s0, s15);
        const v2f f0b = step(B, Ccd, Csd, Cca2, Csa2, Csa, Cca, Ch,
                             pE1B, pE2B, recB, s0, s15);
        if (s0) {
            bufc[vloc][p] = f0a;
            bufc[vloc + 16][p] = f0b;
        }

        asm volatile("s_waitcnt lgkmcnt(0)"
                     : "=s"(A0), "=s"(A1) : "0"(B0), "1"(B1));
    }

    // ---- epilogue: magnitude * PD, coalesced float4 stores ----
    __syncthreads();
    float4* out4 = (float4*)out;
#pragma unroll
    for (int i = 0; i < 2; ++i) {
        const int q = i * 256 + t;
        const int r = q >> 4;              // voxel row (0..31)
        const int c = (q & 15) * 4;        // pulse col
        const float PDr = qmaps[blockIdx.x * 32 + r];
        const v2f a = bufc[r][c],     b = bufc[r][c + 1];
        const v2f d = bufc[r][c + 2], e = bufc[r][c + 3];
        float4 val;
        val.x = sqrtf(a.x * a.x + a.y * a.y) * PDr;
        val.y = sqrtf(b.x * b.x + b.y * b.y) * PDr;
        val.z = sqrtf(d.x * d.x + d.y * d.y) * PDr;
        val.w = sqrtf(e.x * e.x + e.y * e.y) * PDr;
        out4[blockIdx.x * 512 + q] = val;
    }
}

extern "C" void kernel_launch(void* const* d_in, const int* in_sizes, int n_in,
                              void* d_out, int out_size, void* d_ws, size_t ws_size,
                              hipStream_t stream) {
    const float* theta_re = (const float*)d_in[0];
    const float* theta_im = (const float*)d_in[1];
    const float* TRp      = (const float*)d_in[2];
    const float* qmaps    = (const float*)d_in[3];
    float* out = (float*)d_out;
    float* cw  = (float*)d_ws;                 // [65][16] floats = 4160 B
    const int V = in_sizes[3] / 3;             // qmaps is [3, V, 1]
    coef_kernel<<<dim3(1), dim3(128), 0, stream>>>(theta_re, theta_im, cw);
    epg_kernel<<<dim3(V / 32), dim3(256), 0, stream>>>(TRp, qmaps, cw, out, V);
}

// Round 14
// 103.624 us; speedup vs baseline: 1.2569x; 1.0482x over previous
//
#include <hip/hip_runtime.h>
#include <math.h>

// EPG GRE F0, NP2=64 pulses, V voxels.
// 16 lanes per voxel: lane sub (0..15) holds levels k0=sub (slot0), k1=16+sub (slot1).
// Slot-packed r/i-split state, v_pk_fma_f32 rows, SMEM-streamed coefficients,
// Rz-factorized RF (R11) with deferred relax, 2 voxels/lane ILP (R12).
// ROUND 14: R13's 3-phase live-cone structure with the DPP encoding FIX:
// the scalar-phase M-shift (k <- k+1, dest lane i <- lane i+1, lane15 <- 0)
// is row_shl:1 = 0x101, NOT row_shr:1 = 0x111 (which is dest <- lane i-1,
// the P direction -- that was R13's bug; phase B's ROR15 was always correct).
//   A: p in [0,15)  slot1 == 0       -> scalar f32 ops on slot0 only (2 cyc vs 4)
//   B: p in [15,48) both slots live  -> pk body (proven R12)
//   C: p in [48,64) slot1 dead cone  -> scalar slot0 only
// Exactness: matvec is block-diagonal in k; information moves one level per
// pulse via the shift. Pre-matvec level k at pulse p affects F0 only if
// k + p <= 63 -> slot1 (k>=16) is irrelevant for p >= 48; junk entering
// level15 at end of pulse p>=48 has 15+(p+1) > 63 -> dead. Up-ramp: levels
// > p are exactly zero; lane15's architectural 0 on row_shl:1 equals M'_16=0.

#define NP2 64
#define ROR1  0x121   // row_ror:1 : dest lane i <- lane (i-1) & 15   (P: k <- k-1)
#define ROR15 0x12F   // row_ror:15: dest lane i <- lane (i+1) & 15   (M: k <- k+1)
#define RSHL1 0x101   // row_shl:1 : dest lane i <- lane i+1; lane15 <- 0 (bound_ctrl)

typedef float v2f __attribute__((ext_vector_type(2)));
typedef float v8f __attribute__((ext_vector_type(8)));

template<int CTRL>
__device__ __forceinline__ float rowrot(float x) {
    return __int_as_float(
        __builtin_amdgcn_mov_dpp(__float_as_int(x), CTRL, 0xF, 0xF, true));
}
__device__ __forceinline__ v2f mk2(float a, float b) { v2f r; r.x = a; r.y = b; return r; }

#define PAIR(V, i)  __builtin_shufflevector((V), (V), (i), (i) + 1)
#define FMA2(a, b, c) __builtin_elementwise_fma((a), (b), (c))

// ---- pre-kernel: coefficient pair table [65][16] in d_ws ----
// row p: [cd,cd, sd,sd, ca2,ca2, sa2,sa2][sa,sa, ca,ca, h,h, 0,0]
// cd+i*sd = e^{i(phi_{p-1}-phi_p)} from unit vectors (no atan2); phi_{-1}=0.
__global__ void coef_kernel(const float* __restrict__ theta_re,
                            const float* __restrict__ theta_im,
                            float* __restrict__ cw)
{
    const int t = threadIdx.x;
    if (t < NP2) {
        const float tre = theta_re[t], tim = theta_im[t];
        const float a2 = tre * tre + tim * tim;
        const float inva = __frsqrt_rn(a2);        // |theta| >= 0.1
        const float a = a2 * inva;
        const float c = tre * inva, s = tim * inva;   // cos/sin(phi_p)
        float cp = 1.f, sp = 0.f;                     // cos/sin(phi_{p-1})
        if (t > 0) {
            const float ure = theta_re[t - 1], uim = theta_im[t - 1];
            const float ia = __frsqrt_rn(ure * ure + uim * uim);
            cp = ure * ia; sp = uim * ia;
        }
        const float cd = cp * c + sp * s;          // cos(phi_{p-1}-phi_p)
        const float sd = sp * c - cp * s;          // sin(phi_{p-1}-phi_p)
        float sa, ca;
        __sincosf(a, &sa, &ca);
        const float ca2 = 0.5f + 0.5f * ca;        // cos^2(a/2)
        const float sa2 = 0.5f - 0.5f * ca;        // sin^2(a/2)
        const float h = 0.5f * sa;
        float4* row = (float4*)(cw + t * 16);
        row[0] = make_float4(cd, cd, sd, sd);
        row[1] = make_float4(ca2, ca2, sa2, sa2);
        row[2] = make_float4(sa, sa, ca, ca);
        row[3] = make_float4(h, h, 0.f, 0.f);
    } else if (t < NP2 + 4) {
        ((float4*)(cw + NP2 * 16))[t - NP2] = make_float4(0.f, 0.f, 0.f, 0.f);
    }
}

struct St { v2f Pr, Pi, Mr, Mi, Zr, Zi; };

// ---- pk step: both slots (phase B); returns raw F~0 pair (valid on sub0) ----
__device__ __forceinline__ v2f step_pk(St& S,
    v2f Ccd, v2f Csd, v2f Cca2, v2f Csa2, v2f Csa, v2f Cca, v2f Ch,
    v2f pE1, v2f pE2, v2f rec, bool s0, bool s15)
{
    const v2f ec = pE2 * Ccd, es = pE2 * Csd;
    const v2f hPr = FMA2(ec, S.Pr, -(es * S.Pi));
    const v2f hPi = FMA2(ec, S.Pi,  (es * S.Pr));
    const v2f hMr = FMA2(ec, S.Mr,  (es * S.Mi));
    const v2f hMi = FMA2(ec, S.Mi, -(es * S.Mr));
    const v2f ezr = FMA2(pE1, S.Zr, rec);
    const v2f ezi = pE1 * S.Zi;
    const v2f szr = Csa * ezr, szi = Csa * ezi;
    const v2f nPr = FMA2(Cca2, hPr, FMA2(Csa2, hMr,  szi));
    const v2f nPi = FMA2(Cca2, hPi, FMA2(Csa2, hMi, -szr));
    const v2f nMr = FMA2(Csa2, hPr, FMA2(Cca2, hMr, -szi));
    const v2f nMi = FMA2(Csa2, hPi, FMA2(Cca2, hMi,  szr));
    const v2f d1 = hPi - hMi, d2 = hMr - hPr;
    S.Zr = FMA2(Ch, d1, Cca * ezr);
    S.Zi = FMA2(Ch, d2, Cca * ezi);
    const float rPrx = rowrot<ROR1>(nPr.x),  rPry = rowrot<ROR1>(nPr.y);
    const float rPix = rowrot<ROR1>(nPi.x),  rPiy = rowrot<ROR1>(nPi.y);
    const float rMrx = rowrot<ROR15>(nMr.x), rMry = rowrot<ROR15>(nMr.y);
    const float rMix = rowrot<ROR15>(nMi.x), rMiy = rowrot<ROR15>(nMi.y);
    S.Pr.y = s0 ?  rPrx : rPry;
    S.Pi.y = s0 ?  rPix : rPiy;
    S.Pr.x = s0 ?  rMrx : rPrx;
    S.Pi.x = s0 ? -rMix : rPix;
    S.Mr.x = s15 ? rMry : rMrx;
    S.Mi.x = s15 ? rMiy : rMix;
    S.Mr.y = s15 ? 0.f : rMry;
    S.Mi.y = s15 ? 0.f : rMiy;
    return mk2(nPr.x, nPi.x);
}

// ---- scalar step: slot0 only (phases A and C); slot1 (.y) untouched ----
__device__ __forceinline__ v2f step_sc(St& S,
    float cd, float sd, float ca2, float sa2, float sa, float ca, float h,
    float E1, float E2, float rec, bool s0)
{
    const float ec = E2 * cd, es = E2 * sd;
    const float hPr = fmaf(ec, S.Pr.x, -(es * S.Pi.x));
    const float hPi = fmaf(ec, S.Pi.x,  (es * S.Pr.x));
    const float hMr = fmaf(ec, S.Mr.x,  (es * S.Mi.x));
    const float hMi = fmaf(ec, S.Mi.x, -(es * S.Mr.x));
    const float ezr = fmaf(E1, S.Zr.x, rec);
    const float ezi = E1 * S.Zi.x;
    const float szr = sa * ezr, szi = sa * ezi;
    const float nPr = fmaf(ca2, hPr, fmaf(sa2, hMr,  szi));
    const float nPi = fmaf(ca2, hPi, fmaf(sa2, hMi, -szr));
    const float nMr = fmaf(sa2, hPr, fmaf(ca2, hMr, -szi));
    const float nMi = fmaf(sa2, hPi, fmaf(ca2, hMi,  szr));
    S.Zr.x = fmaf(h, hPi - hMi, ca * ezr);
    S.Zi.x = fmaf(h, hMr - hPr, ca * ezi);
    const float rPr = rowrot<ROR1>(nPr);
    const float rPi = rowrot<ROR1>(nPi);
    const float rMr = rowrot<RSHL1>(nMr);   // lane i <- i+1; lane15 <- 0 (bound)
    const float rMi = rowrot<RSHL1>(nMi);
    S.Pr.x = s0 ?  rMr : rPr;               // level0 <- conj(M'_1)
    S.Pi.x = s0 ? -rMi : rPi;
    S.Mr.x = rMr;                           // lane15: 0 (A: exact; C: dead)
    S.Mi.x = rMi;
    return mk2(nPr, nPi);
}

__global__ __launch_bounds__(256, 8) void epg_kernel(
    const float* __restrict__ TRp,
    const float* __restrict__ qmaps,
    const float* __restrict__ cw,
    float* __restrict__ out, int V)
{
    const int t = threadIdx.x;
    const int sub = t & 15;           // lane within voxel group
    const int vloc = t >> 4;          // 0..15
    const int vA = blockIdx.x * 32 + vloc;
    const int vB = vA + 16;

    __shared__ __align__(16) v2f bufc[32][65];   // [vloc][pulse] raw F~0, +1 pad

    const float tr = TRp[0];
    const float E1A = __expf(-tr / qmaps[V + vA]);
    const float E2A = __expf(-tr / qmaps[2 * V + vA]);
    const float E1B = __expf(-tr / qmaps[V + vB]);
    const float E2B = __expf(-tr / qmaps[2 * V + vB]);
    const bool s0 = (sub == 0);
    const bool s15 = (sub == 15);
    const v2f pE1A = mk2(E1A, E1A), pE2A = mk2(E2A, E2A);
    const v2f pE1B = mk2(E1B, E1B), pE2B = mk2(E2B, E2B);
    const float recAs = s0 ? (1.f - E1A) : 0.f;
    const float recBs = s0 ? (1.f - E1B) : 0.f;
    const v2f recA = mk2(recAs, 0.f);
    const v2f recB = mk2(recBs, 0.f);

    St A, B;
    A.Pr = mk2(0.f, 0.f); A.Pi = A.Pr; A.Mr = A.Pr; A.Mi = A.Pr; A.Zr = A.Pr; A.Zi = A.Pr;
    B = A;
    if (s0) { A.Zr.x = 1.0f; B.Zr.x = 1.0f; }   // E1*1 + (1-E1) = 1: exact at p=0

    // ---- SMEM double-buffered coefficient stream (scalar pipe) ----
    v8f A0, A1, B0, B1;
    asm volatile("s_load_dwordx8 %0, %1, 0x0"  : "=s"(B0) : "s"(cw));
    asm volatile("s_load_dwordx8 %0, %1, 0x20" : "=s"(B1) : "s"(cw));
    asm volatile("s_waitcnt lgkmcnt(0)"
                 : "=s"(A0), "=s"(A1) : "0"(B0), "1"(B1));

#define PREFETCH(p)                                                        \
    {                                                                      \
        const float* nx = cw + ((p) + 1) * 16;                             \
        asm volatile("s_load_dwordx8 %0, %1, 0x0"  : "=s"(B0) : "s"(nx));  \
        asm volatile("s_load_dwordx8 %0, %1, 0x20" : "=s"(B1) : "s"(nx));  \
    }
#define CONSUME()                                                          \
    asm volatile("s_waitcnt lgkmcnt(0)"                                    \
                 : "=s"(A0), "=s"(A1) : "0"(B0), "1"(B1));

    // ---- phase A: p in [0,15), slot1 exactly zero -> scalar slot0 only ----
#pragma unroll 1
    for (int p = 0; p < 15; ++p) {
        PREFETCH(p)
        const float cd = A0[0], sd = A0[2], ca2 = A0[4], sa2 = A0[6];
        const float sa = A1[0], ca = A1[2], h = A1[4];
        const v2f f0a = step_sc(A, cd, sd, ca2, sa2, sa, ca, h, E1A, E2A, recAs, s0);
        const v2f f0b = step_sc(B, cd, sd, ca2, sa2, sa, ca, h, E1B, E2B, recBs, s0);
        if (s0) { bufc[vloc][p] = f0a; bufc[vloc + 16][p] = f0b; }
        CONSUME()
    }

    // ---- phase B: p in [15,48), both slots live -> packed body ----
#pragma unroll 1
    for (int p = 15; p < 48; ++p) {
        PREFETCH(p)
        const v2f Ccd  = PAIR(A0, 0), Csd  = PAIR(A0, 2);
        const v2f Cca2 = PAIR(A0, 4), Csa2 = PAIR(A0, 6);
        const v2f Csa  = PAIR(A1, 0), Cca  = PAIR(A1, 2), Ch = PAIR(A1, 4);
        const v2f f0a = step_pk(A, Ccd, Csd, Cca2, Csa2, Csa, Cca, Ch,
                                pE1A, pE2A, recA, s0, s15);
        const v2f f0b = step_pk(B, Ccd, Csd, Cca2, Csa2, Csa, Cca, Ch,
                                pE1B, pE2B, recB, s0, s15);
        if (s0) { bufc[vloc][p] = f0a; bufc[vloc + 16][p] = f0b; }
        CONSUME()
    }

    // ---- phase C: p in [48,64), slot1 in the dead cone -> scalar slot0 only ----
#pragma unroll 1
    for (int p = 48; p < NP2; ++p) {
        PREFETCH(p)
        const float cd = A0[0], sd = A0[2], ca2 = A0[4], sa2 = A0[6];
        const float sa = A1[0], ca = A1[2], h = A1[4];
        const v2f f0a = step_sc(A, cd, sd, ca2, sa2, sa, ca, h, E1A, E2A, recAs, s0);
        const v2f f0b = step_sc(B, cd, sd, ca2, sa2, sa, ca, h, E1B, E2B, recBs, s0);
        if (s0) { bufc[vloc][p] = f0a; bufc[vloc + 16][p] = f0b; }
        CONSUME()
    }

    // ---- epilogue: magnitude * PD, coalesced float4 stores ----
    __syncthreads();
    float4* out4 = (float4*)out;
#pragma unroll
    for (int i = 0; i < 2; ++i) {
        const int q = i * 256 + t;
        const int r = q >> 4;              // voxel row (0..31)
        const int c = (q & 15) * 4;        // pulse col
        const float PDr = qmaps[blockIdx.x * 32 + r];
        const v2f a = bufc[r][c],     b = bufc[r][c + 1];
        const v2f d = bufc[r][c + 2], e = bufc[r][c + 3];
        float4 val;
        val.x = sqrtf(a.x * a.x + a.y * a.y) * PDr;
        val.y = sqrtf(b.x * b.x + b.y * b.y) * PDr;
        val.z = sqrtf(d.x * d.x + d.y * d.y) * PDr;
        val.w = sqrtf(e.x * e.x + e.y * e.y) * PDr;
        out4[blockIdx.x * 512 + q] = val;
    }
}

extern "C" void kernel_launch(void* const* d_in, const int* in_sizes, int n_in,
                              void* d_out, int out_size, void* d_ws, size_t ws_size,
                              hipStream_t stream) {
    const float* theta_re = (const float*)d_in[0];
    const float* theta_im = (const float*)d_in[1];
    const float* TRp      = (const float*)d_in[2];
    const float* qmaps    = (const float*)d_in[3];
    float* out = (float*)d_out;
    float* cw  = (float*)d_ws;                 // [65][16] floats = 4160 B
    const int V = in_sizes[3] / 3;             // qmaps is [3, V, 1]
    coef_kernel<<<dim3(1), dim3(128), 0, stream>>>(theta_re, theta_im, cw);
    epg_kernel<<<dim3(V / 32), dim3(256), 0, stream>>>(TRp, qmaps, cw, out, V);
}

// Round 15
// 101.677 us; speedup vs baseline: 1.2809x; 1.0191x over previous
//
#include <hip/hip_runtime.h>
#include <math.h>

// EPG GRE F0, NP2=64 pulses, V voxels.
// 16 lanes per voxel: lane sub (0..15) holds levels k0=sub (slot0), k1=16+sub (slot1).
// Slot-packed r/i-split state, v_pk_fma_f32 rows, SMEM-streamed coefficients,
// Rz-factorized RF (R11) with deferred relax.
// ROUND 15: back to 1 voxel/lane (8192 waves = 8/SIMD, R11's ~95%-efficiency
// config) combined with R14's 3-phase live-cone:
//   A: p in [0,15)  slot1 == 0       -> scalar f32 slot0 only
//   B: p in [15,48) both slots live  -> pk body
//   C: p in [48,64) slot1 dead cone  -> scalar slot0 only
// R12/R14's 2-voxel ILP halved TLP (4 waves/SIMD) and dropped issue efficiency
// to ~68%; R11's 8 waves ran ~95%. Same pipe work as R14, better coverage.
// Exactness (R14, passing): matvec block-diagonal in k; shift moves one level
// per pulse; pre-matvec level k at pulse p affects F0 only if k+p <= 63 ->
// slot1 dead for p >= 48; lane15's architectural 0 on row_shl:1 equals M'_16=0
// in phase A and is dead in phase C; up-ramp levels > p exactly zero.

#define NP2 64
#define ROR1  0x121   // row_ror:1 : dest lane i <- lane (i-1) & 15   (P: k <- k-1)
#define ROR15 0x12F   // row_ror:15: dest lane i <- lane (i+1) & 15   (M: k <- k+1)
#define RSHL1 0x101   // row_shl:1 : dest lane i <- lane i+1; lane15 <- 0 (bound_ctrl)

typedef float v2f __attribute__((ext_vector_type(2)));
typedef float v8f __attribute__((ext_vector_type(8)));

template<int CTRL>
__device__ __forceinline__ float rowrot(float x) {
    return __int_as_float(
        __builtin_amdgcn_mov_dpp(__float_as_int(x), CTRL, 0xF, 0xF, true));
}
__device__ __forceinline__ v2f mk2(float a, float b) { v2f r; r.x = a; r.y = b; return r; }

#define PAIR(V, i)  __builtin_shufflevector((V), (V), (i), (i) + 1)
#define FMA2(a, b, c) __builtin_elementwise_fma((a), (b), (c))

// ---- pre-kernel: coefficient pair table [65][16] in d_ws ----
// row p: [cd,cd, sd,sd, ca2,ca2, sa2,sa2][sa,sa, ca,ca, h,h, 0,0]
// cd+i*sd = e^{i(phi_{p-1}-phi_p)} from unit vectors (no atan2); phi_{-1}=0.
__global__ void coef_kernel(const float* __restrict__ theta_re,
                            const float* __restrict__ theta_im,
                            float* __restrict__ cw)
{
    const int t = threadIdx.x;
    if (t < NP2) {
        const float tre = theta_re[t], tim = theta_im[t];
        const float a2 = tre * tre + tim * tim;
        const float inva = __frsqrt_rn(a2);        // |theta| >= 0.1
        const float a = a2 * inva;
        const float c = tre * inva, s = tim * inva;   // cos/sin(phi_p)
        float cp = 1.f, sp = 0.f;                     // cos/sin(phi_{p-1})
        if (t > 0) {
            const float ure = theta_re[t - 1], uim = theta_im[t - 1];
            const float ia = __frsqrt_rn(ure * ure + uim * uim);
            cp = ure * ia; sp = uim * ia;
        }
        const float cd = cp * c + sp * s;          // cos(phi_{p-1}-phi_p)
        const float sd = sp * c - cp * s;          // sin(phi_{p-1}-phi_p)
        float sa, ca;
        __sincosf(a, &sa, &ca);
        const float ca2 = 0.5f + 0.5f * ca;        // cos^2(a/2)
        const float sa2 = 0.5f - 0.5f * ca;        // sin^2(a/2)
        const float h = 0.5f * sa;
        float4* row = (float4*)(cw + t * 16);
        row[0] = make_float4(cd, cd, sd, sd);
        row[1] = make_float4(ca2, ca2, sa2, sa2);
        row[2] = make_float4(sa, sa, ca, ca);
        row[3] = make_float4(h, h, 0.f, 0.f);
    } else if (t < NP2 + 4) {
        ((float4*)(cw + NP2 * 16))[t - NP2] = make_float4(0.f, 0.f, 0.f, 0.f);
    }
}

struct St { v2f Pr, Pi, Mr, Mi, Zr, Zi; };

// ---- pk step: both slots (phase B); returns raw F~0 pair (valid on sub0) ----
__device__ __forceinline__ v2f step_pk(St& S,
    v2f Ccd, v2f Csd, v2f Cca2, v2f Csa2, v2f Csa, v2f Cca, v2f Ch,
    v2f pE1, v2f pE2, v2f rec, bool s0, bool s15)
{
    const v2f ec = pE2 * Ccd, es = pE2 * Csd;
    const v2f hPr = FMA2(ec, S.Pr, -(es * S.Pi));
    const v2f hPi = FMA2(ec, S.Pi,  (es * S.Pr));
    const v2f hMr = FMA2(ec, S.Mr,  (es * S.Mi));
    const v2f hMi = FMA2(ec, S.Mi, -(es * S.Mr));
    const v2f ezr = FMA2(pE1, S.Zr, rec);
    const v2f ezi = pE1 * S.Zi;
    const v2f szr = Csa * ezr, szi = Csa * ezi;
    const v2f nPr = FMA2(Cca2, hPr, FMA2(Csa2, hMr,  szi));
    const v2f nPi = FMA2(Cca2, hPi, FMA2(Csa2, hMi, -szr));
    const v2f nMr = FMA2(Csa2, hPr, FMA2(Cca2, hMr, -szi));
    const v2f nMi = FMA2(Csa2, hPi, FMA2(Cca2, hMi,  szr));
    const v2f d1 = hPi - hMi, d2 = hMr - hPr;
    S.Zr = FMA2(Ch, d1, Cca * ezr);
    S.Zi = FMA2(Ch, d2, Cca * ezi);
    const float rPrx = rowrot<ROR1>(nPr.x),  rPry = rowrot<ROR1>(nPr.y);
    const float rPix = rowrot<ROR1>(nPi.x),  rPiy = rowrot<ROR1>(nPi.y);
    const float rMrx = rowrot<ROR15>(nMr.x), rMry = rowrot<ROR15>(nMr.y);
    const float rMix = rowrot<ROR15>(nMi.x), rMiy = rowrot<ROR15>(nMi.y);
    S.Pr.y = s0 ?  rPrx : rPry;
    S.Pi.y = s0 ?  rPix : rPiy;
    S.Pr.x = s0 ?  rMrx : rPrx;
    S.Pi.x = s0 ? -rMix : rPix;
    S.Mr.x = s15 ? rMry : rMrx;
    S.Mi.x = s15 ? rMiy : rMix;
    S.Mr.y = s15 ? 0.f : rMry;
    S.Mi.y = s15 ? 0.f : rMiy;
    return mk2(nPr.x, nPi.x);
}

// ---- scalar step: slot0 only (phases A and C); slot1 (.y) untouched ----
__device__ __forceinline__ v2f step_sc(St& S,
    float cd, float sd, float ca2, float sa2, float sa, float ca, float h,
    float E1, float E2, float rec, bool s0)
{
    const float ec = E2 * cd, es = E2 * sd;
    const float hPr = fmaf(ec, S.Pr.x, -(es * S.Pi.x));
    const float hPi = fmaf(ec, S.Pi.x,  (es * S.Pr.x));
    const float hMr = fmaf(ec, S.Mr.x,  (es * S.Mi.x));
    const float hMi = fmaf(ec, S.Mi.x, -(es * S.Mr.x));
    const float ezr = fmaf(E1, S.Zr.x, rec);
    const float ezi = E1 * S.Zi.x;
    const float szr = sa * ezr, szi = sa * ezi;
    const float nPr = fmaf(ca2, hPr, fmaf(sa2, hMr,  szi));
    const float nPi = fmaf(ca2, hPi, fmaf(sa2, hMi, -szr));
    const float nMr = fmaf(sa2, hPr, fmaf(ca2, hMr, -szi));
    const float nMi = fmaf(sa2, hPi, fmaf(ca2, hMi,  szr));
    S.Zr.x = fmaf(h, hPi - hMi, ca * ezr);
    S.Zi.x = fmaf(h, hMr - hPr, ca * ezi);
    const float rPr = rowrot<ROR1>(nPr);
    const float rPi = rowrot<ROR1>(nPi);
    const float rMr = rowrot<RSHL1>(nMr);   // lane i <- i+1; lane15 <- 0 (bound)
    const float rMi = rowrot<RSHL1>(nMi);
    S.Pr.x = s0 ?  rMr : rPr;               // level0 <- conj(M'_1)
    S.Pi.x = s0 ? -rMi : rPi;
    S.Mr.x = rMr;                           // lane15: 0 (A: exact; C: dead)
    S.Mi.x = rMi;
    return mk2(nPr, nPi);
}

__global__ __launch_bounds__(256, 8) void epg_kernel(
    const float* __restrict__ TRp,
    const float* __restrict__ qmaps,
    const float* __restrict__ cw,
    float* __restrict__ out, int V)
{
    const int t = threadIdx.x;
    const int sub = t & 15;           // lane within voxel group
    const int vloc = t >> 4;          // 0..15 local voxel
    const int v = blockIdx.x * 16 + vloc;

    __shared__ __align__(16) v2f bufc[16][65];   // [vloc][pulse] raw F~0, +1 pad

    const float tr = TRp[0];
    const float E1 = __expf(-tr / qmaps[V + v]);
    const float E2 = __expf(-tr / qmaps[2 * V + v]);
    const bool s0 = (sub == 0);
    const bool s15 = (sub == 15);
    const v2f pE1 = mk2(E1, E1), pE2 = mk2(E2, E2);
    const float recs = s0 ? (1.f - E1) : 0.f;
    const v2f rec = mk2(recs, 0.f);

    St A;
    A.Pr = mk2(0.f, 0.f); A.Pi = A.Pr; A.Mr = A.Pr; A.Mi = A.Pr; A.Zr = A.Pr; A.Zi = A.Pr;
    if (s0) A.Zr.x = 1.0f;            // E1*1 + (1-E1) = 1: exact at p=0

    // ---- SMEM double-buffered coefficient stream (scalar pipe) ----
    v8f A0, A1, B0, B1;
    asm volatile("s_load_dwordx8 %0, %1, 0x0"  : "=s"(B0) : "s"(cw));
    asm volatile("s_load_dwordx8 %0, %1, 0x20" : "=s"(B1) : "s"(cw));
    asm volatile("s_waitcnt lgkmcnt(0)"
                 : "=s"(A0), "=s"(A1) : "0"(B0), "1"(B1));

#define PREFETCH(p)                                                        \
    {                                                                      \
        const float* nx = cw + ((p) + 1) * 16;                             \
        asm volatile("s_load_dwordx8 %0, %1, 0x0"  : "=s"(B0) : "s"(nx));  \
        asm volatile("s_load_dwordx8 %0, %1, 0x20" : "=s"(B1) : "s"(nx));  \
    }
#define CONSUME()                                                          \
    asm volatile("s_waitcnt lgkmcnt(0)"                                    \
                 : "=s"(A0), "=s"(A1) : "0"(B0), "1"(B1));

    // ---- phase A: p in [0,15), slot1 exactly zero -> scalar slot0 only ----
#pragma unroll 1
    for (int p = 0; p < 15; ++p) {
        PREFETCH(p)
        const float cd = A0[0], sd = A0[2], ca2 = A0[4], sa2 = A0[6];
        const float sa = A1[0], ca = A1[2], h = A1[4];
        const v2f f0 = step_sc(A, cd, sd, ca2, sa2, sa, ca, h, E1, E2, recs, s0);
        if (s0) bufc[vloc][p] = f0;
        CONSUME()
    }

    // ---- phase B: p in [15,48), both slots live -> packed body ----
#pragma unroll 1
    for (int p = 15; p < 48; ++p) {
        PREFETCH(p)
        const v2f Ccd  = PAIR(A0, 0), Csd  = PAIR(A0, 2);
        const v2f Cca2 = PAIR(A0, 4), Csa2 = PAIR(A0, 6);
        const v2f Csa  = PAIR(A1, 0), Cca  = PAIR(A1, 2), Ch = PAIR(A1, 4);
        const v2f f0 = step_pk(A, Ccd, Csd, Cca2, Csa2, Csa, Cca, Ch,
                               pE1, pE2, rec, s0, s15);
        if (s0) bufc[vloc][p] = f0;
        CONSUME()
    }

    // ---- phase C: p in [48,64), slot1 in the dead cone -> scalar slot0 only ----
#pragma unroll 1
    for (int p = 48; p < NP2; ++p) {
        PREFETCH(p)
        const float cd = A0[0], sd = A0[2], ca2 = A0[4], sa2 = A0[6];
        const float sa = A1[0], ca = A1[2], h = A1[4];
        const v2f f0 = step_sc(A, cd, sd, ca2, sa2, sa, ca, h, E1, E2, recs, s0);
        if (s0) bufc[vloc][p] = f0;
        CONSUME()
    }

    // ---- epilogue: magnitude * PD, coalesced float4 stores ----
    __syncthreads();
    const int r = t >> 4;              // voxel row
    const int c = (t & 15) * 4;        // pulse col
    const float PDr = qmaps[blockIdx.x * 16 + r];
    const v2f a = bufc[r][c],     b = bufc[r][c + 1];
    const v2f d = bufc[r][c + 2], e = bufc[r][c + 3];
    float4 val;
    val.x = sqrtf(a.x * a.x + a.y * a.y) * PDr;
    val.y = sqrtf(b.x * b.x + b.y * b.y) * PDr;
    val.z = sqrtf(d.x * d.x + d.y * d.y) * PDr;
    val.w = sqrtf(e.x * e.x + e.y * e.y) * PDr;
    ((float4*)out)[blockIdx.x * 256 + t] = val;
}

extern "C" void kernel_launch(void* const* d_in, const int* in_sizes, int n_in,
                              void* d_out, int out_size, void* d_ws, size_t ws_size,
                              hipStream_t stream) {
    const float* theta_re = (const float*)d_in[0];
    const float* theta_im = (const float*)d_in[1];
    const float* TRp      = (const float*)d_in[2];
    const float* qmaps    = (const float*)d_in[3];
    float* out = (float*)d_out;
    float* cw  = (float*)d_ws;                 // [65][16] floats = 4160 B
    const int V = in_sizes[3] / 3;             // qmaps is [3, V, 1]
    coef_kernel<<<dim3(1), dim3(128), 0, stream>>>(theta_re, theta_im, cw);
    epg_kernel<<<dim3(V / 16), dim3(256), 0, stream>>>(TRp, qmaps, cw, out, V);
}

// Round 18
// 101.288 us; speedup vs baseline: 1.2859x; 1.0038x over previous
//
#include <hip/hip_runtime.h>
#include <math.h>

// EPG GRE F0, NP2=64 pulses, V voxels.
// 16 lanes per voxel: lane sub (0..15) holds levels k0=sub (slot0), k1=16+sub (slot1).
// Slot-packed r/i-split state, v_pk_fma_f32 rows, Rz-factorized RF (R11) with
// deferred relax, 3-phase live-cone (R14), 1 voxel/lane (R15).
// ROUND 18: coefficient stream via PLAIN C++ float4 global loads, software-
// pipelined one iteration ahead in registers. No inline asm anywhere:
//  - R16/R17 NaN'd because any asm constraint naming in-flight s_load dest
//    SGPRs can make the allocator copy them BEFORE the waitcnt (garbage).
//    Compiler-managed loads are sound by construction.
//  - Bonus: coefficient loads retire on vmcnt, the F0 ds_write on lgkmcnt ->
//    they never share a wait. The compiler waits vmcnt only at the cur=nxt
//    rotation (a full body of hiding) and never lgkm-waits the store. This is
//    the sound implementation of the R16 "don't wait on your own ds_write"
//    theory.
// Phases: A p<15 scalar slot0; B 15..47 pk both slots; C 48..63 scalar slot0.
// Exactness (R14/R15, passing): matvec block-diagonal in k; shift moves one
// level per pulse; pre-matvec level k at pulse p affects F0 only if k+p <= 63
// -> slot1 dead for p >= 48; lane15's architectural 0 on row_shl:1 equals
// M'_16=0 in phase A and is dead in phase C; up-ramp levels > p exactly zero.

#define NP2 64
#define ROR1  0x121   // row_ror:1 : dest lane i <- lane (i-1) & 15   (P: k <- k-1)
#define ROR15 0x12F   // row_ror:15: dest lane i <- lane (i+1) & 15   (M: k <- k+1)
#define RSHL1 0x101   // row_shl:1 : dest lane i <- lane i+1; lane15 <- 0 (bound_ctrl)

typedef float v2f __attribute__((ext_vector_type(2)));

template<int CTRL>
__device__ __forceinline__ float rowrot(float x) {
    return __int_as_float(
        __builtin_amdgcn_mov_dpp(__float_as_int(x), CTRL, 0xF, 0xF, true));
}
__device__ __forceinline__ v2f mk2(float a, float b) { v2f r; r.x = a; r.y = b; return r; }

#define FMA2(a, b, c) __builtin_elementwise_fma((a), (b), (c))

// ---- pre-kernel: coefficient pair table [65][16] in d_ws ----
// row p (4 float4s): q0=[cd,cd,sd,sd] q1=[ca2,ca2,sa2,sa2] q2=[sa,sa,ca,ca]
// q3=[h,h,0,0]; cd+i*sd = e^{i(phi_{p-1}-phi_p)} from unit vectors; phi_{-1}=0;
// row 64 = zero pad (prefetch overrun target).
__global__ void coef_kernel(const float* __restrict__ theta_re,
                            const float* __restrict__ theta_im,
                            float* __restrict__ cw)
{
    const int t = threadIdx.x;
    if (t < NP2) {
        const float tre = theta_re[t], tim = theta_im[t];
        const float a2 = tre * tre + tim * tim;
        const float inva = __frsqrt_rn(a2);        // |theta| >= 0.1
        const float a = a2 * inva;
        const float c = tre * inva, s = tim * inva;   // cos/sin(phi_p)
        float cp = 1.f, sp = 0.f;                     // cos/sin(phi_{p-1})
        if (t > 0) {
            const float ure = theta_re[t - 1], uim = theta_im[t - 1];
            const float ia = __frsqrt_rn(ure * ure + uim * uim);
            cp = ure * ia; sp = uim * ia;
        }
        const float cd = cp * c + sp * s;          // cos(phi_{p-1}-phi_p)
        const float sd = sp * c - cp * s;          // sin(phi_{p-1}-phi_p)
        float sa, ca;
        __sincosf(a, &sa, &ca);
        const float ca2 = 0.5f + 0.5f * ca;        // cos^2(a/2)
        const float sa2 = 0.5f - 0.5f * ca;        // sin^2(a/2)
        const float h = 0.5f * sa;
        float4* row = (float4*)(cw + t * 16);
        row[0] = make_float4(cd, cd, sd, sd);
        row[1] = make_float4(ca2, ca2, sa2, sa2);
        row[2] = make_float4(sa, sa, ca, ca);
        row[3] = make_float4(h, h, 0.f, 0.f);
    } else if (t < NP2 + 4) {
        ((float4*)(cw + NP2 * 16))[t - NP2] = make_float4(0.f, 0.f, 0.f, 0.f);
    }
}

struct St { v2f Pr, Pi, Mr, Mi, Zr, Zi; };

// ---- pk step: both slots (phase B); returns raw F~0 pair (valid on sub0) ----
__device__ __forceinline__ v2f step_pk(St& S,
    v2f Ccd, v2f Csd, v2f Cca2, v2f Csa2, v2f Csa, v2f Cca, v2f Ch,
    v2f pE1, v2f pE2, v2f rec, bool s0, bool s15)
{
    const v2f ec = pE2 * Ccd, es = pE2 * Csd;
    const v2f hPr = FMA2(ec, S.Pr, -(es * S.Pi));
    const v2f hPi = FMA2(ec, S.Pi,  (es * S.Pr));
    const v2f hMr = FMA2(ec, S.Mr,  (es * S.Mi));
    const v2f hMi = FMA2(ec, S.Mi, -(es * S.Mr));
    const v2f ezr = FMA2(pE1, S.Zr, rec);
    const v2f ezi = pE1 * S.Zi;
    const v2f szr = Csa * ezr, szi = Csa * ezi;
    const v2f nPr = FMA2(Cca2, hPr, FMA2(Csa2, hMr,  szi));
    const v2f nPi = FMA2(Cca2, hPi, FMA2(Csa2, hMi, -szr));
    const v2f nMr = FMA2(Csa2, hPr, FMA2(Cca2, hMr, -szi));
    const v2f nMi = FMA2(Csa2, hPi, FMA2(Cca2, hMi,  szr));
    const v2f d1 = hPi - hMi, d2 = hMr - hPr;
    S.Zr = FMA2(Ch, d1, Cca * ezr);
    S.Zi = FMA2(Ch, d2, Cca * ezi);
    const float rPrx = rowrot<ROR1>(nPr.x),  rPry = rowrot<ROR1>(nPr.y);
    const float rPix = rowrot<ROR1>(nPi.x),  rPiy = rowrot<ROR1>(nPi.y);
    const float rMrx = rowrot<ROR15>(nMr.x), rMry = rowrot<ROR15>(nMr.y);
    const float rMix = rowrot<ROR15>(nMi.x), rMiy = rowrot<ROR15>(nMi.y);
    S.Pr.y = s0 ?  rPrx : rPry;
    S.Pi.y = s0 ?  rPix : rPiy;
    S.Pr.x = s0 ?  rMrx : rPrx;
    S.Pi.x = s0 ? -rMix : rPix;
    S.Mr.x = s15 ? rMry : rMrx;
    S.Mi.x = s15 ? rMiy : rMix;
    S.Mr.y = s15 ? 0.f : rMry;
    S.Mi.y = s15 ? 0.f : rMiy;
    return mk2(nPr.x, nPi.x);
}

// ---- scalar step: slot0 only (phases A and C); slot1 (.y) untouched ----
__device__ __forceinline__ v2f step_sc(St& S,
    float cd, float sd, float ca2, float sa2, float sa, float ca, float h,
    float E1, float E2, float rec, bool s0)
{
    const float ec = E2 * cd, es = E2 * sd;
    const float hPr = fmaf(ec, S.Pr.x, -(es * S.Pi.x));
    const float hPi = fmaf(ec, S.Pi.x,  (es * S.Pr.x));
    const float hMr = fmaf(ec, S.Mr.x,  (es * S.Mi.x));
    const float hMi = fmaf(ec, S.Mi.x, -(es * S.Mr.x));
    const float ezr = fmaf(E1, S.Zr.x, rec);
    const float ezi = E1 * S.Zi.x;
    const float szr = sa * ezr, szi = sa * ezi;
    const float nPr = fmaf(ca2, hPr, fmaf(sa2, hMr,  szi));
    const float nPi = fmaf(ca2, hPi, fmaf(sa2, hMi, -szr));
    const float nMr = fmaf(sa2, hPr, fmaf(ca2, hMr, -szi));
    const float nMi = fmaf(sa2, hPi, fmaf(ca2, hMi,  szr));
    S.Zr.x = fmaf(h, hPi - hMi, ca * ezr);
    S.Zi.x = fmaf(h, hMr - hPr, ca * ezi);
    const float rPr = rowrot<ROR1>(nPr);
    const float rPi = rowrot<ROR1>(nPi);
    const float rMr = rowrot<RSHL1>(nMr);   // lane i <- i+1; lane15 <- 0 (bound)
    const float rMi = rowrot<RSHL1>(nMi);
    S.Pr.x = s0 ?  rMr : rPr;               // level0 <- conj(M'_1)
    S.Pi.x = s0 ? -rMi : rPi;
    S.Mr.x = rMr;                           // lane15: 0 (A: exact; C: dead)
    S.Mi.x = rMi;
    return mk2(nPr, nPi);
}

__global__ __launch_bounds__(256, 8) void epg_kernel(
    const float* __restrict__ TRp,
    const float* __restrict__ qmaps,
    const float* __restrict__ cw,
    float* __restrict__ out, int V)
{
    const int t = threadIdx.x;
    const int sub = t & 15;           // lane within voxel group
    const int vloc = t >> 4;          // 0..15 local voxel
    const int v = blockIdx.x * 16 + vloc;

    __shared__ __align__(16) v2f bufc[16][65];   // [vloc][pulse] raw F~0, +1 pad

    const float tr = TRp[0];
    const float E1 = __expf(-tr / qmaps[V + v]);
    const float E2 = __expf(-tr / qmaps[2 * V + v]);
    const bool s0 = (sub == 0);
    const bool s15 = (sub == 15);
    const v2f pE1 = mk2(E1, E1), pE2 = mk2(E2, E2);
    const float recs = s0 ? (1.f - E1) : 0.f;
    const v2f rec = mk2(recs, 0.f);

    St A;
    A.Pr = mk2(0.f, 0.f); A.Pi = A.Pr; A.Mr = A.Pr; A.Mi = A.Pr; A.Zr = A.Pr; A.Zi = A.Pr;
    if (s0) A.Zr.x = 1.0f;            // E1*1 + (1-E1) = 1: exact at p=0

    // ---- coefficient stream: plain global float4 loads, 1-iteration prefetch.
    // Wave-uniform addresses -> one L1-resident cacheline per row; compiler
    // inserts vmcnt waits at the cur=nxt rotation (a full body of hiding).
    const float4* __restrict__ cwq = (const float4*)cw;
    float4 q0 = cwq[0], q1 = cwq[1], q2 = cwq[2], q3 = cwq[3];

    // ---- phase A: p in [0,15), slot1 exactly zero -> scalar slot0 only ----
#pragma unroll 1
    for (int p = 0; p < 15; ++p) {
        const int nb = 4 * (p + 1);
        const float4 n0 = cwq[nb], n1 = cwq[nb + 1];
        const float4 n2 = cwq[nb + 2], n3 = cwq[nb + 3];
        const v2f f0 = step_sc(A, q0.x, q0.z, q1.x, q1.z, q2.x, q2.z, q3.x,
                               E1, E2, recs, s0);
        if (s0) bufc[vloc][p] = f0;
        q0 = n0; q1 = n1; q2 = n2; q3 = n3;
    }

    // ---- phase B: p in [15,48), both slots live -> packed body ----
#pragma unroll 1
    for (int p = 15; p < 48; ++p) {
        const int nb = 4 * (p + 1);
        const float4 n0 = cwq[nb], n1 = cwq[nb + 1];
        const float4 n2 = cwq[nb + 2], n3 = cwq[nb + 3];
        const v2f Ccd  = mk2(q0.x, q0.y), Csd  = mk2(q0.z, q0.w);
        const v2f Cca2 = mk2(q1.x, q1.y), Csa2 = mk2(q1.z, q1.w);
        const v2f Csa  = mk2(q2.x, q2.y), Cca  = mk2(q2.z, q2.w);
        const v2f Ch   = mk2(q3.x, q3.y);
        const v2f f0 = step_pk(A, Ccd, Csd, Cca2, Csa2, Csa, Cca, Ch,
                               pE1, pE2, rec, s0, s15);
        if (s0) bufc[vloc][p] = f0;
        q0 = n0; q1 = n1; q2 = n2; q3 = n3;
    }

    // ---- phase C: p in [48,64), slot1 in the dead cone -> scalar slot0 only ----
#pragma unroll 1
    for (int p = 48; p < NP2; ++p) {
        const int nb = 4 * (p + 1);
        const float4 n0 = cwq[nb], n1 = cwq[nb + 1];
        const float4 n2 = cwq[nb + 2], n3 = cwq[nb + 3];
        const v2f f0 = step_sc(A, q0.x, q0.z, q1.x, q1.z, q2.x, q2.z, q3.x,
                               E1, E2, recs, s0);
        if (s0) bufc[vloc][p] = f0;
        q0 = n0; q1 = n1; q2 = n2; q3 = n3;
    }

    // ---- epilogue: magnitude * PD, coalesced float4 stores ----
    __syncthreads();
    const int r = t >> 4;              // voxel row
    const int c = (t & 15) * 4;        // pulse col
    const float PDr = qmaps[blockIdx.x * 16 + r];
    const v2f a = bufc[r][c],     b = bufc[r][c + 1];
    const v2f d = bufc[r][c + 2], e = bufc[r][c + 3];
    float4 val;
    val.x = sqrtf(a.x * a.x + a.y * a.y) * PDr;
    val.y = sqrtf(b.x * b.x + b.y * b.y) * PDr;
    val.z = sqrtf(d.x * d.x + d.y * d.y) * PDr;
    val.w = sqrtf(e.x * e.x + e.y * e.y) * PDr;
    ((float4*)out)[blockIdx.x * 256 + t] = val;
}

extern "C" void kernel_launch(void* const* d_in, const int* in_sizes, int n_in,
                              void* d_out, int out_size, void* d_ws, size_t ws_size,
                              hipStream_t stream) {
    const float* theta_re = (const float*)d_in[0];
    const float* theta_im = (const float*)d_in[1];
    const float* TRp      = (const float*)d_in[2];
    const float* qmaps    = (const float*)d_in[3];
    float* out = (float*)d_out;
    float* cw  = (float*)d_ws;                 // [65][16] floats = 4160 B
    const int V = in_sizes[3] / 3;             // qmaps is [3, V, 1]
    coef_kernel<<<dim3(1), dim3(128), 0, stream>>>(theta_re, theta_im, cw);
    epg_kernel<<<dim3(V / 16), dim3(256), 0, stream>>>(TRp, qmaps, cw, out, V);
}

// Round 19
// 98.287 us; speedup vs baseline: 1.3251x; 1.0305x over previous
//
#include <hip/hip_runtime.h>
#include <hip/hip_fp16.h>
#include <math.h>

// EPG GRE F0, NP2=64 pulses, V voxels.
// 16 lanes per voxel-pair: lane sub (0..15) holds levels k0=sub (slot0),
// k1=16+sub (slot1) for TWO voxels packed in the f16 halves of each 32-bit reg
// (voxA = lo half, voxB = hi half). v_pk_fma_f16 = 2x the f32 pipe rate.
// ROUND 19: f16 voxel-pair packing. All control flow (DPP shifts, boundary
// selects, bound_ctrl zeros) acts on whole 32-bit regs -> bit-identical
// structure to the passing R15/R18 kernel for both voxels simultaneously.
// Rz-factorized RF (R11) with deferred relax, 3-phase live-cone (R14).
// Coefficients pre-packed as duplicated-f16 uints (no converts in hot loop);
// F0 stored packed, converted to f32 + magnitude + PD only in the epilogue.
// Phases: A p<15 slot0 only; B 15..47 both slots; C 48..63 slot0 only.
// Exactness (R14-R18, passing): matvec block-diagonal in k; shift moves one
// level per pulse; pre-matvec level k at pulse p affects F0 only if k+p <= 63
// -> slot1 dead for p >= 48; lane15's architectural 0 on row_shl:1 equals
// M'_16=0 in phase A and is dead in phase C; up-ramp levels > p exactly zero.

#define NP2 64
#define ROR1  0x121   // row_ror:1 : dest lane i <- lane (i-1) & 15   (P: k <- k-1)
#define ROR15 0x12F   // row_ror:15: dest lane i <- lane (i+1) & 15   (M: k <- k+1)
#define RSHL1 0x101   // row_shl:1 : dest lane i <- lane i+1; lane15 <- 0 (bound_ctrl)

__device__ __forceinline__ unsigned h2u(__half2 x) {
    unsigned u; __builtin_memcpy(&u, &x, 4); return u;
}
__device__ __forceinline__ __half2 u2h(unsigned u) {
    __half2 h; __builtin_memcpy(&h, &u, 4); return h;
}
template<int CTRL>
__device__ __forceinline__ __half2 rroth(__half2 x) {
    return u2h((unsigned)__builtin_amdgcn_mov_dpp((int)h2u(x), CTRL, 0xF, 0xF, true));
}

// ---- pre-kernel: coefficient table [65][8] uints in d_ws ----
// row p: [cd sd ca2 sa2 sa ca h 0], each uint = duplicated f16 pair.
// cd+i*sd = e^{i(phi_{p-1}-phi_p)} from unit vectors; phi_{-1}=0; row 64 = pad.
__global__ void coef_kernel(const float* __restrict__ theta_re,
                            const float* __restrict__ theta_im,
                            unsigned* __restrict__ cw)
{
    const int t = threadIdx.x;
    if (t < NP2) {
        const float tre = theta_re[t], tim = theta_im[t];
        const float a2 = tre * tre + tim * tim;
        const float inva = __frsqrt_rn(a2);        // |theta| >= 0.1
        const float a = a2 * inva;
        const float c = tre * inva, s = tim * inva;   // cos/sin(phi_p)
        float cp = 1.f, sp = 0.f;                     // cos/sin(phi_{p-1})
        if (t > 0) {
            const float ure = theta_re[t - 1], uim = theta_im[t - 1];
            const float ia = __frsqrt_rn(ure * ure + uim * uim);
            cp = ure * ia; sp = uim * ia;
        }
        const float cd = cp * c + sp * s;          // cos(phi_{p-1}-phi_p)
        const float sd = sp * c - cp * s;          // sin(phi_{p-1}-phi_p)
        float sa, ca;
        __sincosf(a, &sa, &ca);
        const float ca2 = 0.5f + 0.5f * ca;        // cos^2(a/2)
        const float sa2 = 0.5f - 0.5f * ca;        // sin^2(a/2)
        unsigned* row = cw + t * 8;
        const float vals[8] = { cd, sd, ca2, sa2, sa, ca, 0.5f * sa, 0.f };
        for (int j = 0; j < 8; ++j) {
            const __half h = __float2half(vals[j]);
            __half2 hp = __halves2half2(h, h);
            unsigned u; __builtin_memcpy(&u, &hp, 4);
            row[j] = u;
        }
    } else if (t < NP2 + 8) {
        cw[NP2 * 8 + (t - NP2)] = 0u;              // zero pad row (prefetch target)
    }
}

// one slot's matvec (both voxels via f16 halves); outputs unshifted nP/nM, updates Z
__device__ __forceinline__ void slot_mat(
    __half2 Pr, __half2 Pi, __half2 Mr, __half2 Mi, __half2& Zr, __half2& Zi,
    __half2 ec, __half2 es, __half2 esn,
    __half2 ca2, __half2 sa2, __half2 sa, __half2 ca, __half2 hh,
    __half2 pE1, __half2 rec,
    __half2& nPr, __half2& nPi, __half2& nMr, __half2& nMi)
{
    const __half2 hPr = __hfma2(ec, Pr, __hmul2(esn, Pi));
    const __half2 hPi = __hfma2(ec, Pi, __hmul2(es,  Pr));
    const __half2 hMr = __hfma2(ec, Mr, __hmul2(es,  Mi));
    const __half2 hMi = __hfma2(ec, Mi, __hmul2(esn, Mr));
    const __half2 ezr = __hfma2(pE1, Zr, rec);
    const __half2 ezi = __hmul2(pE1, Zi);
    const __half2 szr = __hmul2(sa, ezr);
    const __half2 szi = __hmul2(sa, ezi);
    const __half2 szrn = __hneg2(szr);
    const __half2 szin = __hneg2(szi);
    nPr = __hfma2(ca2, hPr, __hfma2(sa2, hMr, szi));
    nPi = __hfma2(ca2, hPi, __hfma2(sa2, hMi, szrn));
    nMr = __hfma2(sa2, hPr, __hfma2(ca2, hMr, szin));
    nMi = __hfma2(sa2, hPi, __hfma2(ca2, hMi, szr));
    Zr = __hfma2(hh, __hsub2(hPi, hMi), __hmul2(ca, ezr));
    Zi = __hfma2(hh, __hsub2(hMr, hPr), __hmul2(ca, ezi));
}

__global__ __launch_bounds__(256, 8) void epg_kernel(
    const float* __restrict__ TRp,
    const float* __restrict__ qmaps,
    const unsigned* __restrict__ cw,
    float* __restrict__ out, int V)
{
    const int t = threadIdx.x;
    const int sub = t & 15;           // lane within voxel group
    const int vloc = t >> 4;          // 0..15
    const int vA = blockIdx.x * 32 + vloc;   // lo f16 half
    const int vB = vA + 16;                  // hi f16 half

    __shared__ unsigned bufPr[16][65], bufPi[16][65];  // packed F~0 (re/im), +1 pad

    const float tr = TRp[0];
    const float E1A = __expf(-tr / qmaps[V + vA]);
    const float E2A = __expf(-tr / qmaps[2 * V + vA]);
    const float E1B = __expf(-tr / qmaps[V + vB]);
    const float E2B = __expf(-tr / qmaps[2 * V + vB]);
    const bool s0 = (sub == 0);
    const bool s15 = (sub == 15);
    const __half2 pE1 = __floats2half2_rn(E1A, E1B);
    const __half2 pE2 = __floats2half2_rn(E2A, E2B);
    const __half2 zeroH = __floats2half2_rn(0.f, 0.f);
    const __half2 recH = s0 ? __floats2half2_rn(1.f - E1A, 1.f - E1B) : zeroH;

    // slot-packed state, 2 voxels per reg (f16 halves)
    __half2 Pr0 = zeroH, Pr1 = zeroH, Pi0 = zeroH, Pi1 = zeroH;
    __half2 Mr0 = zeroH, Mr1 = zeroH, Mi0 = zeroH, Mi1 = zeroH;
    __half2 Zr0 = s0 ? __floats2half2_rn(1.f, 1.f) : zeroH;   // E1*1+(1-E1)=1 exact
    __half2 Zr1 = zeroH, Zi0 = zeroH, Zi1 = zeroH;

    // coefficient stream: plain uint4 loads, 1-iteration register prefetch
    const uint4* __restrict__ cwq = (const uint4*)cw;
    uint4 q0 = cwq[0], q1 = cwq[1];

    __half2 nPr0, nPi0, nMr0, nMi0, nPr1, nPi1, nMr1, nMi1;

    // ---- phase A: p in [0,15), slot1 exactly zero -> slot0 only ----
#pragma unroll 1
    for (int p = 0; p < 15; ++p) {
        const int nb = 2 * (p + 1);
        const uint4 n0 = cwq[nb], n1 = cwq[nb + 1];
        const __half2 ec = __hmul2(pE2, u2h(q0.x));
        const __half2 es = __hmul2(pE2, u2h(q0.y));
        const __half2 esn = __hneg2(es);
        slot_mat(Pr0, Pi0, Mr0, Mi0, Zr0, Zi0, ec, es, esn,
                 u2h(q0.z), u2h(q0.w), u2h(q1.x), u2h(q1.y), u2h(q1.z),
                 pE1, recH, nPr0, nPi0, nMr0, nMi0);
        if (s0) { bufPr[vloc][p] = h2u(nPr0); bufPi[vloc][p] = h2u(nPi0); }
        const __half2 rPr = rroth<ROR1>(nPr0);
        const __half2 rPi = rroth<ROR1>(nPi0);
        const __half2 rMr = rroth<RSHL1>(nMr0);  // lane i <- i+1; lane15 <- 0
        const __half2 rMi = rroth<RSHL1>(nMi0);
        Pr0 = s0 ? rMr : rPr;                    // level0 <- conj(M'_1)
        Pi0 = s0 ? __hneg2(rMi) : rPi;
        Mr0 = rMr;                               // lane15: 0 (exact: M'_16 = 0)
        Mi0 = rMi;
        q0 = n0; q1 = n1;
    }

    // ---- phase B: p in [15,48), both slots live ----
#pragma unroll 1
    for (int p = 15; p < 48; ++p) {
        const int nb = 2 * (p + 1);
        const uint4 n0 = cwq[nb], n1 = cwq[nb + 1];
        const __half2 ec = __hmul2(pE2, u2h(q0.x));
        const __half2 es = __hmul2(pE2, u2h(q0.y));
        const __half2 esn = __hneg2(es);
        const __half2 ca2 = u2h(q0.z), sa2 = u2h(q0.w);
        const __half2 sa = u2h(q1.x), ca = u2h(q1.y), hh = u2h(q1.z);
        slot_mat(Pr0, Pi0, Mr0, Mi0, Zr0, Zi0, ec, es, esn,
                 ca2, sa2, sa, ca, hh, pE1, recH, nPr0, nPi0, nMr0, nMi0);
        slot_mat(Pr1, Pi1, Mr1, Mi1, Zr1, Zi1, ec, es, esn,
                 ca2, sa2, sa, ca, hh, pE1, zeroH, nPr1, nPi1, nMr1, nMi1);
        if (s0) { bufPr[vloc][p] = h2u(nPr0); bufPi[vloc][p] = h2u(nPi0); }
        const __half2 rPr0 = rroth<ROR1>(nPr0),  rPr1 = rroth<ROR1>(nPr1);
        const __half2 rPi0 = rroth<ROR1>(nPi0),  rPi1 = rroth<ROR1>(nPi1);
        const __half2 rMr0 = rroth<ROR15>(nMr0), rMr1 = rroth<ROR15>(nMr1);
        const __half2 rMi0 = rroth<ROR15>(nMi0), rMi1 = rroth<ROR15>(nMi1);
        Pr1 = s0 ? rPr0 : rPr1;                  // level16 <- P'_15
        Pi1 = s0 ? rPi0 : rPi1;
        Pr0 = s0 ? rMr0 : rPr0;                  // level0 <- conj(M'_1)
        Pi0 = s0 ? __hneg2(rMi0) : rPi0;
        Mr0 = s15 ? rMr1 : rMr0;                 // level15 <- M'_16
        Mi0 = s15 ? rMi1 : rMi0;
        Mr1 = s15 ? zeroH : rMr1;                // level31 <- M'_32 = 0 exactly
        Mi1 = s15 ? zeroH : rMi1;
        q0 = n0; q1 = n1;
    }

    // ---- phase C: p in [48,64), slot1 in the dead cone -> slot0 only ----
#pragma unroll 1
    for (int p = 48; p < NP2; ++p) {
        const int nb = 2 * (p + 1);
        const uint4 n0 = cwq[nb], n1 = cwq[nb + 1];
        const __half2 ec = __hmul2(pE2, u2h(q0.x));
        const __half2 es = __hmul2(pE2, u2h(q0.y));
        const __half2 esn = __hneg2(es);
        slot_mat(Pr0, Pi0, Mr0, Mi0, Zr0, Zi0, ec, es, esn,
                 u2h(q0.z), u2h(q0.w), u2h(q1.x), u2h(q1.y), u2h(q1.z),
                 pE1, recH, nPr0, nPi0, nMr0, nMi0);
        if (s0) { bufPr[vloc][p] = h2u(nPr0); bufPi[vloc][p] = h2u(nPi0); }
        const __half2 rPr = rroth<ROR1>(nPr0);
        const __half2 rPi = rroth<ROR1>(nPi0);
        const __half2 rMr = rroth<RSHL1>(nMr0);  // lane15's junk: dead cone
        const __half2 rMi = rroth<RSHL1>(nMi0);
        Pr0 = s0 ? rMr : rPr;
        Pi0 = s0 ? __hneg2(rMi) : rPi;
        Mr0 = rMr;
        Mi0 = rMi;
        q0 = n0; q1 = n1;
    }

    // ---- epilogue: unpack f16 halves, magnitude * PD (f32), coalesced stores ----
    __syncthreads();
    float4* out4 = (float4*)out;
#pragma unroll
    for (int i = 0; i < 2; ++i) {
        const int q = i * 256 + t;
        const int r = q >> 4;              // output voxel row 0..31
        const int c = (q & 15) * 4;        // pulse col
        const int row = r & 15;            // state row
        const bool hi = (r >> 4) != 0;     // which f16 half
        const float PDr = qmaps[blockIdx.x * 32 + r];
        float4 val;
        float* vp = &val.x;
#pragma unroll
        for (int j = 0; j < 4; ++j) {
            const __half2 hr = u2h(bufPr[row][c + j]);
            const __half2 hii = u2h(bufPi[row][c + j]);
            const float pr = hi ? __high2float(hr) : __low2float(hr);
            const float pi = hi ? __high2float(hii) : __low2float(hii);
            vp[j] = sqrtf(pr * pr + pi * pi) * PDr;
        }
        out4[blockIdx.x * 512 + q] = val;
    }
}

extern "C" void kernel_launch(void* const* d_in, const int* in_sizes, int n_in,
                              void* d_out, int out_size, void* d_ws, size_t ws_size,
                              hipStream_t stream) {
    const float* theta_re = (const float*)d_in[0];
    const float* theta_im = (const float*)d_in[1];
    const float* TRp      = (const float*)d_in[2];
    const float* qmaps    = (const float*)d_in[3];
    float* out = (float*)d_out;
    unsigned* cw = (unsigned*)d_ws;            // [65][8] uints = 2080 B
    const int V = in_sizes[3] / 3;             // qmaps is [3, V, 1]
    coef_kernel<<<dim3(1), dim3(128), 0, stream>>>(theta_re, theta_im, cw);
    epg_kernel<<<dim3(V / 32), dim3(256), 0, stream>>>(TRp, qmaps, cw, out, V);
}